// Round 12
// baseline (701.698 us; speedup 1.0000x reference)
//
#include <hip/hip_runtime.h>
#include <hip/hip_bf16.h>
#include <cstdint>
#include <cstddef>

// ---------------- problem constants (fixed by setup_inputs) ----------------
constexpr int B_  = 8;
constexpr int N_  = 2048;
constexpr int KNB = 20;
constexpr int MN  = B_ * N_;        // 16384 points
constexpr int CAT_C = 512;          // concat channels 64+64+128+256
constexpr float EPS = 1e-5f;

typedef __attribute__((ext_vector_type(8))) short bf16x8;
typedef __attribute__((ext_vector_type(4))) float f32x4;

// ---------------- workspace layout (units: floats) ----------------
constexpr size_t alignup64(size_t x){ return (x + 63) & ~size_t(63); }
constexpr size_t STATS   = 0;                          // 7 layers * 4 replicas * 2048 (S1@+0, S2@+1024)
constexpr size_t NSTATS  = size_t(7) * 4 * 2048;       // 57344
constexpr size_t MISC    = STATS + NSTATS;             // [0]=nvalid [1]=n_ok [2]=flag
constexpr size_t SCALEO  = alignup64(MISC + 16);
constexpr size_t SHIFTO  = SCALEO + 7 * 1024;
constexpr size_t VALID8  = alignup64(SHIFTO + 7 * 1024);                 // MN*KNB bytes
constexpr size_t OK8     = alignup64(VALID8 + (size_t(MN)*KNB + 3) / 4); // MN bytes
constexpr size_t WENC    = alignup64(OK8 + (MN + 3) / 4);   // wcomb: f32 (L0) or bf16 (L1-3)
constexpr size_t WLAST   = WENC  + 32768;    // 1024x512 bf16
constexpr size_t WEMB1   = WLAST + 262144;   // 512x1024 bf16
constexpr size_t WEMB2   = WEMB1 + 262144;   // 128x512 bf16
constexpr size_t XT      = WEMB2 + 32768;
constexpr size_t XCATB   = alignup64(XT + size_t(MN) * 4);   // bf16 MN x 512
constexpr size_t HHOFF   = XCATB + size_t(MN) * 256;         // f32 MN x 512
constexpr size_t HMAXO   = HHOFF + size_t(MN) * 512;         // f32 MN x 256
constexpr size_t HMINO   = HMAXO + size_t(MN) * 256;         // f32 MN x 256
constexpr size_t YLB     = HMINO + size_t(MN) * 256;         // bf16 MN x 1024 (raw, pre-BN)
// aliases after enc phase: yemb1_bf = HMAXO (bf16 MNx512, raw), yemb2_f32 = HMINO (f32 MNx128, raw),
//                          yout_f32 = HHOFF (f32 MNx32).  Total ~121 MB.

__device__ inline float bf2f(unsigned short u){
    unsigned int x = ((unsigned int)u) << 16;
    return __builtin_bit_cast(float, x);
}
__device__ inline unsigned short f2bf(float f){
    __hip_bfloat16 h = __float2bfloat16(f);
    return __builtin_bit_cast(unsigned short, h);
}
__device__ inline unsigned int packbf(float a, float b){
    return (unsigned int)f2bf(a) | ((unsigned int)f2bf(b) << 16);
}
__device__ inline void gl16(const void* g, void* l){
    __builtin_amdgcn_global_load_lds(
        (const __attribute__((address_space(1))) void*)g,
        (__attribute__((address_space(3))) void*)l, 16, 0, 0);
}

// ---------------- small utility kernels ----------------

__global__ __launch_bounds__(256) void detect_valid_kernel(const unsigned char* __restrict__ v, int* __restrict__ flag){
    __shared__ int f;
    if (threadIdx.x == 0) f = 1;
    __syncthreads();
    int ok = 1;
    #pragma unroll
    for (int it = 0; it < 4; ++it){
        int g = threadIdx.x + it * 256;
        unsigned char b0 = v[4*g], b1 = v[4*g+1], b2 = v[4*g+2], b3 = v[4*g+3];
        if ((b1 | b2 | b3) != 0 || b0 > 1) ok = 0;
    }
    if (!ok) atomicAnd(&f, 0);
    __syncthreads();
    if (threadIdx.x == 0) *flag = f;
}

__global__ __launch_bounds__(256) void expand_ok_kernel(const void* __restrict__ vin,
        unsigned char* __restrict__ v8, unsigned char* __restrict__ ok,
        float* __restrict__ nvalid, float* __restrict__ n_ok, const int* __restrict__ flag){
    const int p = blockIdx.x * 256 + threadIdx.x;   // MN exact multiple of 256
    int cnt = 0, anyv = 0;
    unsigned char loc[KNB];
    if (*flag){
        const int* vi = ((const int*)vin) + (size_t)p * KNB;
        #pragma unroll
        for (int k = 0; k < KNB; ++k){ int b = (vi[k] != 0); loc[k] = (unsigned char)b; cnt += b; anyv |= b; }
    } else {
        const unsigned char* vb = ((const unsigned char*)vin) + (size_t)p * KNB;
        #pragma unroll
        for (int k = 0; k < KNB; ++k){ int b = (vb[k] != 0); loc[k] = (unsigned char)b; cnt += b; anyv |= b; }
    }
    unsigned char* dst = v8 + (size_t)p * KNB;
    #pragma unroll
    for (int k = 0; k < KNB; ++k) dst[k] = loc[k];
    ok[p] = (unsigned char)anyv;
    float fc = (float)cnt;
    #pragma unroll
    for (int o = 32; o > 0; o >>= 1) fc += __shfl_down(fc, o);
    unsigned long long m = __ballot(anyv != 0);
    if ((threadIdx.x & 63) == 0){
        if (fc > 0.f) unsafeAtomicAdd(nvalid, fc);
        if (m)        unsafeAtomicAdd(n_ok, (float)__popcll(m));
    }
}

// x (B,3,N) -> xT (B*N, 4) row-major (pad 4th with 0)
__global__ __launch_bounds__(256) void transpose_x_kernel(const float* __restrict__ x, float* __restrict__ xt){
    int i = blockIdx.x * 256 + threadIdx.x;
    if (i >= MN) return;
    int b = i / N_, n = i % N_;
    float4 v;
    v.x = x[(size_t)(b*3 + 0) * N_ + n];
    v.y = x[(size_t)(b*3 + 1) * N_ + n];
    v.z = x[(size_t)(b*3 + 2) * N_ + n];
    v.w = 0.f;
    ((float4*)xt)[i] = v;
}

// W (O,2C) -> Wcomb (2O,C) f32
__global__ __launch_bounds__(256) void build_wcomb_f32_kernel(const float* __restrict__ W, float* __restrict__ wc,
        int O, int C){
    int i = blockIdx.x * 256 + threadIdx.x;
    if (i >= 2 * O * C) return;
    int r = i / C, c = i % C;
    float v;
    if (r < O) v = W[(size_t)r * (2*C) + c];
    else       v = W[(size_t)(r-O) * (2*C) + C + c] - W[(size_t)(r-O) * (2*C) + c];
    wc[i] = v;
}

// same but emits bf16
__global__ __launch_bounds__(256) void build_wcomb_bf16_kernel(const float* __restrict__ W, unsigned short* __restrict__ wc,
        int O, int C){
    int i = blockIdx.x * 256 + threadIdx.x;
    if (i >= 2 * O * C) return;
    int r = i / C, c = i % C;
    float v;
    if (r < O) v = W[(size_t)r * (2*C) + c];
    else       v = W[(size_t)(r-O) * (2*C) + C + c] - W[(size_t)(r-O) * (2*C) + c];
    wc[i] = f2bf(v);
}

// all three dense-weight conversions in one kernel (f32 -> bf16, float4 granules)
__global__ __launch_bounds__(256) void convert3_bf16_kernel(
        const float* __restrict__ a, const float* __restrict__ b, const float* __restrict__ c,
        unsigned short* __restrict__ wa, unsigned short* __restrict__ wb, unsigned short* __restrict__ wcc){
    int i = blockIdx.x * 256 + threadIdx.x;
    if (i >= 278528) return;
    const float* src; unsigned short* dst; int off;
    if (i < 131072)      { src = a; dst = wa;  off = i; }
    else if (i < 262144) { src = b; dst = wb;  off = i - 131072; }
    else                 { src = c; dst = wcc; off = i - 262144; }
    float4 v = ((const float4*)src)[off];
    ushort4 o;
    o.x = f2bf(v.x); o.y = f2bf(v.y); o.z = f2bf(v.z); o.w = f2bf(v.w);
    ((ushort4*)dst)[off] = o;
}

// ---------------- f32 tiled GEMM (enc1 K=3; out layer O=32 with optional fused BN+lrelu on X) ----------------
__global__ __launch_bounds__(256) void gemm_f32(
        const float* __restrict__ X, const float* __restrict__ W,
        float* __restrict__ Y, const float* __restrict__ bias,
        int M, int K, int O, int lda, int ldy,
        const float* __restrict__ scX, const float* __restrict__ shX)
{
    __shared__ float Xs[16][68];
    __shared__ float Ws[16][68];
    const int tid = threadIdx.x;
    const int tx = tid & 15, ty = tid >> 4;
    const int m0 = blockIdx.x * 64, o0 = blockIdx.y * 64;
    float acc[4][4] = {};
    for (int k0 = 0; k0 < K; k0 += 16){
        #pragma unroll
        for (int i = 0; i < 4; ++i){
            int e = tid + i * 256;
            int r = e >> 4, c = e & 15;
            float xv = 0.f, wv = 0.f;
            if (k0 + c < K){
                xv = X[(size_t)(m0 + r) * lda + k0 + c];
                if (scX){
                    xv = xv * scX[k0 + c] + shX[k0 + c];
                    xv = (xv > 0.f) ? xv : 0.2f * xv;
                }
                if (o0 + r < O) wv = W[(size_t)(o0 + r) * K + k0 + c];
            }
            Xs[c][r] = xv;
            Ws[c][r] = wv;
        }
        __syncthreads();
        #pragma unroll
        for (int kk = 0; kk < 16; ++kk){
            const float4 a4 = *(const float4*)(&Xs[kk][ty * 4]);
            const float4 b4 = *(const float4*)(&Ws[kk][tx * 4]);
            const float a[4] = {a4.x, a4.y, a4.z, a4.w};
            const float b[4] = {b4.x, b4.y, b4.z, b4.w};
            #pragma unroll
            for (int i = 0; i < 4; ++i)
                #pragma unroll
                for (int j = 0; j < 4; ++j)
                    acc[i][j] = fmaf(a[i], b[j], acc[i][j]);
        }
        __syncthreads();
    }
    #pragma unroll
    for (int i = 0; i < 4; ++i){
        int m = m0 + ty * 4 + i;
        int o = o0 + tx * 4;
        if (o < O){
            float4 v;
            v.x = acc[i][0]; v.y = acc[i][1]; v.z = acc[i][2]; v.w = acc[i][3];
            if (bias){
                v.x += bias[o]; v.y += bias[o+1]; v.z += bias[o+2]; v.w += bias[o+3];
            }
            *(float4*)(&Y[(size_t)m * ldy + o]) = v;
        }
    }
}

// ---------------- bf16 MFMA GEMM: Y(M,O) = X(M,K)bf16 @ W(O,K)bf16^T (+bias) ----------------
// m97 structure: 128x128 tile, BK=64, 4 waves 2x2, global_load_lds w=16, XOR chunk-swizzle.
// STATSF: fuse masked per-channel sum/sumsq accumulation (over ok rows) into the epilogue.
// AFFA: fuse per-K-channel affine+lrelu (BN of the PREVIOUS layer) into A staging.
template<bool OBF16, bool STATSF, bool AFFA>
__global__ __launch_bounds__(256) void gemm_bf16_mfma(
        const unsigned short* __restrict__ Xg, const unsigned short* __restrict__ Wg,
        void* __restrict__ Yv, const float* __restrict__ bias,
        int K, int ldx, int ldy,
        const unsigned char* __restrict__ ok, float* __restrict__ statsL,
        const float* __restrict__ scA, const float* __restrict__ shA)
{
    __shared__ unsigned short As[128 * 64];
    __shared__ unsigned short Bs[128 * 64];
    const int t = threadIdx.x;
    const int lane = t & 63;
    const int w = t >> 6;
    const int wr = w >> 1, wc = w & 1;
    const int m0 = blockIdx.x * 128;
    const int o0 = blockIdx.y * 128;

    f32x4 acc[4][4] = {};

    for (int k0 = 0; k0 < K; k0 += 64){
        #pragma unroll
        for (int i = 0; i < 4; ++i){
            int e = i * 256 + t;                 // chunk id (16B each)
            int row = e >> 3;                    // 0..127
            int c = (e & 7) ^ (row & 7);         // pre-swizzled SOURCE chunk (m173 pattern)
            int kk = k0 + c * 8;
            if constexpr (AFFA){
                uint4 a = *(const uint4*)(Xg + (size_t)(m0 + row) * ldx + kk);
                float4 s0 = *(const float4*)&scA[kk], s1 = *(const float4*)&scA[kk + 4];
                float4 h0 = *(const float4*)&shA[kk], h1 = *(const float4*)&shA[kk + 4];
                const float sc[8] = {s0.x,s0.y,s0.z,s0.w, s1.x,s1.y,s1.z,s1.w};
                const float sh[8] = {h0.x,h0.y,h0.z,h0.w, h1.x,h1.y,h1.z,h1.w};
                unsigned int wds[4] = {a.x, a.y, a.z, a.w};
                unsigned int ov[4];
                #pragma unroll
                for (int q = 0; q < 4; ++q){
                    float f0 = bf2f((unsigned short)(wds[q] & 0xffffu)) * sc[2*q]   + sh[2*q];
                    float f1 = bf2f((unsigned short)(wds[q] >> 16))     * sc[2*q+1] + sh[2*q+1];
                    f0 = (f0 > 0.f) ? f0 : 0.2f * f0;
                    f1 = (f1 > 0.f) ? f1 : 0.2f * f1;
                    ov[q] = packbf(f0, f1);
                }
                uint4 o4 = {ov[0], ov[1], ov[2], ov[3]};
                *(uint4*)&As[(size_t)e * 8] = o4;   // same linear LDS dest as gl16
            } else {
                gl16(Xg + (size_t)(m0 + row) * ldx + kk, &As[(size_t)e * 8]);
            }
            gl16(Wg + (size_t)(o0 + row) * K + kk, &Bs[(size_t)e * 8]);
        }
        __syncthreads();
        const int kq = lane >> 4;                // 0..3
        #pragma unroll
        for (int ks = 0; ks < 2; ++ks){
            bf16x8 a[4], b[4];
            #pragma unroll
            for (int mi = 0; mi < 4; ++mi){
                int r = wr * 64 + mi * 16 + (lane & 15);
                int ch = (ks * 4 + kq) ^ (r & 7);
                a[mi] = *(const bf16x8*)&As[r * 64 + ch * 8];
            }
            #pragma unroll
            for (int ni = 0; ni < 4; ++ni){
                int r = wc * 64 + ni * 16 + (lane & 15);
                int ch = (ks * 4 + kq) ^ (r & 7);
                b[ni] = *(const bf16x8*)&Bs[r * 64 + ch * 8];
            }
            #pragma unroll
            for (int mi = 0; mi < 4; ++mi)
                #pragma unroll
                for (int ni = 0; ni < 4; ++ni)
                    acc[mi][ni] = __builtin_amdgcn_mfma_f32_16x16x32_bf16(a[mi], b[ni], acc[mi][ni], 0, 0, 0);
        }
        __syncthreads();
    }

    // C/D layout (m89-verified): col = lane&15, row = (lane>>4)*4 + reg
    float s1l[4] = {}, s2l[4] = {};
    float bi[4];
    #pragma unroll
    for (int ni = 0; ni < 4; ++ni)
        bi[ni] = bias ? bias[o0 + wc * 64 + ni * 16 + (lane & 15)] : 0.f;

    #pragma unroll
    for (int mi = 0; mi < 4; ++mi){
        const int mbase = m0 + wr * 64 + mi * 16 + (lane >> 4) * 4;
        uchar4 okv = {1,1,1,1};
        if constexpr (STATSF) okv = *(const uchar4*)(ok + mbase);
        const unsigned char okarr[4] = {okv.x, okv.y, okv.z, okv.w};
        #pragma unroll
        for (int j = 0; j < 4; ++j){
            const int m = mbase + j;
            #pragma unroll
            for (int ni = 0; ni < 4; ++ni){
                int o = o0 + wc * 64 + ni * 16 + (lane & 15);
                float v = acc[mi][ni][j] + bi[ni];
                if constexpr (STATSF){
                    if (okarr[j]){ s1l[ni] += v; s2l[ni] += v * v; }
                }
                if constexpr (OBF16)
                    ((unsigned short*)Yv)[(size_t)m * ldy + o] = f2bf(v);
                else
                    ((float*)Yv)[(size_t)m * ldy + o] = v;
            }
        }
    }

    if constexpr (STATSF){
        #pragma unroll
        for (int ni = 0; ni < 4; ++ni){
            s1l[ni] += __shfl_xor(s1l[ni], 16); s1l[ni] += __shfl_xor(s1l[ni], 32);
            s2l[ni] += __shfl_xor(s2l[ni], 16); s2l[ni] += __shfl_xor(s2l[ni], 32);
        }
        if ((lane >> 4) == 0){
            float* S = statsL + (size_t)((blockIdx.x + blockIdx.y) & 3) * 2048;
            #pragma unroll
            for (int ni = 0; ni < 4; ++ni){
                int o = o0 + wc * 64 + ni * 16 + lane;
                unsafeAtomicAdd(&S[o],        s1l[ni]);
                unsafeAtomicAdd(&S[1024 + o], s2l[ni]);
            }
        }
    }
}

// ---------------- edge gather: channel-split (64 ch per block via blockIdx.y), lane=channel,
// 2 pts/wave, branchless, XCD-pinned batches, NT stores; hmin only when some gamma<0 ----------------
// gridDim.x = MN/8 (multiple of 8 => blockIdx.x&7 == linear_id&7 == XCD pin preserved);
// gridDim.y = O/64 channel chunks. Per-wave state: 1 channel slot => low VGPR, high occupancy.
__global__ __launch_bounds__(256) void edge_gather_kernel(
        const float* __restrict__ HHp, const int* __restrict__ idx,
        const unsigned char* __restrict__ v8, const float* __restrict__ g,
        float* __restrict__ hmaxo, float* __restrict__ hmino,
        float* __restrict__ statsL, int O)
{
    const int TWO2 = 2 * O;
    const int bid  = blockIdx.x;                 // MN/8 blocks in x
    const int wv   = threadIdx.x >> 6;
    const int lane = threadIdx.x & 63;
    const int ch   = (blockIdx.y << 6) + lane;   // this lane's channel
    const int bat  = bid & 7;                    // batch == XCD (round-robin dispatch)
    const int chunk = bid >> 3;
    const int base = bat << 11;
    const int p0   = base + chunk * 8 + wv * 2;

    const bool needmin = (__ballot(g[ch] < 0.f) != 0ull);

    float s1 = 0.f, s2 = 0.f;
    #pragma unroll
    for (int pi = 0; pi < 2; ++pi){
        const int p = p0 + pi;
        const unsigned int* v32 = (const unsigned int*)(v8 + (size_t)p * KNB);
        unsigned int vb[5];
        #pragma unroll
        for (int q = 0; q < 5; ++q) vb[q] = v32[q];
        int jj[KNB];
        const int4* ip4 = (const int4*)(idx + (size_t)p * KNB);
        #pragma unroll
        for (int q = 0; q < 5; ++q){
            int4 iv = ip4[q];
            jj[q*4+0] = iv.x; jj[q*4+1] = iv.y; jj[q*4+2] = iv.z; jj[q*4+3] = iv.w;
        }
        const float hc = HHp[(size_t)p * TWO2 + O + ch];
        float hmax = -INFINITY, hmin = INFINITY;
        if (needmin){
            #pragma unroll
            for (int k = 0; k < KNB; ++k){
                const bool val = ((vb[k >> 2] >> ((k & 3) * 8)) & 0xffu) != 0;
                float h  = HHp[(size_t)(base + jj[k]) * TWO2 + ch] + hc;
                float hs = val ? h : 0.f;
                s1 += hs; s2 += hs * hs;
                hmax = fmaxf(hmax, val ? h : -INFINITY);
                hmin = fminf(hmin, val ? h :  INFINITY);
            }
        } else {
            #pragma unroll
            for (int k = 0; k < KNB; ++k){
                const bool val = ((vb[k >> 2] >> ((k & 3) * 8)) & 0xffu) != 0;
                float h  = HHp[(size_t)(base + jj[k]) * TWO2 + ch] + hc;
                float hs = val ? h : 0.f;
                s1 += hs; s2 += hs * hs;
                hmax = fmaxf(hmax, val ? h : -INFINITY);
            }
        }
        __builtin_nontemporal_store(hmax, &hmaxo[(size_t)p * O + ch]);
        if (needmin)
            __builtin_nontemporal_store(hmin, &hmino[(size_t)p * O + ch]);
    }
    float* S = statsL + (size_t)(wv & 3) * 2048;
    unsafeAtomicAdd(&S[ch],        s1);
    unsafeAtomicAdd(&S[1024 + ch], s2);
}

// ---------------- BN parameter computation ----------------
__global__ void bn_params_kernel(const float* __restrict__ statsL, const float* __restrict__ cnt,
        const float* __restrict__ g, const float* __restrict__ bta,
        float* __restrict__ scale, float* __restrict__ shift, int O)
{
    int o = blockIdx.x * 256 + threadIdx.x;
    if (o >= O) return;
    float s1 = 0.f, s2 = 0.f;
    #pragma unroll
    for (int r = 0; r < 4; ++r){
        s1 += statsL[(size_t)r * 2048 + o];
        s2 += statsL[(size_t)r * 2048 + 1024 + o];
    }
    float n   = fmaxf(*cnt, 1.0f);
    float mu  = s1 / n;
    float var = fmaxf(s2 / n - mu * mu, 0.f);
    float sc  = g[o] * rsqrtf(var + EPS);
    scale[o] = sc;
    shift[o] = bta[o] - mu * sc;
}

// ---------------- edge finalize: affine+lrelu on masked max -> bf16 concat buffer ----------------
__global__ __launch_bounds__(256) void edge_finalize_kernel(
        const float* __restrict__ hmaxo, const float* __restrict__ hmino,
        const unsigned char* __restrict__ ok,
        const float* __restrict__ scale, const float* __restrict__ shift,
        unsigned short* __restrict__ xcat, int O, int chanoff)
{
    size_t i = (size_t)blockIdx.x * 256 + threadIdx.x;
    size_t p = i / (size_t)O;
    int o = (int)(i - p * (size_t)O);
    float v = 0.f;
    if (ok[p]){
        float sc = scale[o];
        float h;
        if (sc >= 0.f) h = hmaxo[i]; else h = hmino[i];
        v = h * sc + shift[o];
        v = (v > 0.f) ? v : 0.2f * v;
    }
    xcat[p * CAT_C + chanoff + o] = f2bf(v);
}

// ---------------- final transpose (B,N,32) -> (B,32,N) ----------------
__global__ __launch_bounds__(256) void transpose_out_kernel(const float* __restrict__ Y, float* __restrict__ out){
    int i = blockIdx.x * 256 + threadIdx.x;
    int n = i & (N_ - 1);
    int rest = i >> 11;
    int o = rest & 31;
    int b = rest >> 5;
    out[i] = Y[((((size_t)b * N_) + n) << 5) + o];
}

// ---------------- host side ----------------
extern "C" void kernel_launch(void* const* d_in, const int* in_sizes, int n_in,
                              void* d_out, int out_size, void* d_ws, size_t ws_size,
                              hipStream_t stream)
{
    const float* x        = (const float*)d_in[0];
    const int*   idx      = (const int*)  d_in[1];
    const void*  valid_rw = d_in[2];
    const float* enc_w[4] = {(const float*)d_in[3], (const float*)d_in[6], (const float*)d_in[9],  (const float*)d_in[12]};
    const float* enc_g[4] = {(const float*)d_in[4], (const float*)d_in[7], (const float*)d_in[10], (const float*)d_in[13]};
    const float* enc_b[4] = {(const float*)d_in[5], (const float*)d_in[8], (const float*)d_in[11], (const float*)d_in[14]};
    const float* last_w   = (const float*)d_in[15];
    const float* last_g   = (const float*)d_in[16];
    const float* last_b   = (const float*)d_in[17];
    const float* emb_w1   = (const float*)d_in[18];
    const float* emb_bi1  = (const float*)d_in[19];
    const float* emb_g1   = (const float*)d_in[20];
    const float* emb_b1   = (const float*)d_in[21];
    const float* emb_w2   = (const float*)d_in[22];
    const float* emb_bi2  = (const float*)d_in[23];
    const float* emb_g2   = (const float*)d_in[24];
    const float* emb_b2   = (const float*)d_in[25];
    const float* out_w    = (const float*)d_in[26];
    const float* out_bias = (const float*)d_in[27];

    float* ws = (float*)d_ws;
    unsigned char* v8   = (unsigned char*)(ws + VALID8);
    unsigned char* ok8  = (unsigned char*)(ws + OK8);
    unsigned short* xcatb = (unsigned short*)(ws + XCATB);
    unsigned short* ylb   = (unsigned short*)(ws + YLB);
    unsigned short* wlastb = (unsigned short*)(ws + WLAST);
    unsigned short* wemb1b = (unsigned short*)(ws + WEMB1);
    unsigned short* wemb2b = (unsigned short*)(ws + WEMB2);
    float* nvalid = ws + MISC + 0;
    float* n_ok   = ws + MISC + 1;
    int*   flag   = (int*)(ws + MISC + 2);

    hipMemsetAsync(d_ws, 0, (MISC + 16) * sizeof(float), stream);

    detect_valid_kernel<<<1, 256, 0, stream>>>((const unsigned char*)valid_rw, flag);
    expand_ok_kernel<<<MN / 256, 256, 0, stream>>>(valid_rw, v8, ok8, nvalid, n_ok, flag);
    transpose_x_kernel<<<MN / 256, 256, 0, stream>>>(x, ws + XT);
    convert3_bf16_kernel<<<(278528 + 255) / 256, 256, 0, stream>>>(last_w, emb_w1, emb_w2, wlastb, wemb1b, wemb2b);

    const int Cs[4]     = {3, 64, 64, 128};
    const int Os[4]     = {64, 64, 128, 256};
    const int inoff[4]  = {0, 0, 64, 128};
    const int outoff[4] = {0, 64, 128, 256};

    for (int L = 0; L < 4; ++L){
        const int C = Cs[L], O = Os[L], TWO2 = 2 * O;
        if (L == 0){
            build_wcomb_f32_kernel<<<(2*O*C + 255)/256, 256, 0, stream>>>(enc_w[L], ws + WENC, O, C);
            dim3 gg(MN / 64, TWO2 / 64);
            gemm_f32<<<gg, 256, 0, stream>>>(ws + XT, ws + WENC, ws + HHOFF, nullptr, MN, C, TWO2, 4, TWO2, nullptr, nullptr);
        } else {
            build_wcomb_bf16_kernel<<<(2*O*C + 255)/256, 256, 0, stream>>>(enc_w[L], (unsigned short*)(ws + WENC), O, C);
            dim3 gg(MN / 128, TWO2 / 128);
            gemm_bf16_mfma<false, false, false><<<gg, 256, 0, stream>>>(xcatb + inoff[L], (unsigned short*)(ws + WENC),
                    ws + HHOFF, nullptr, C, CAT_C, TWO2, nullptr, nullptr, nullptr, nullptr);
        }
        float* statsL = ws + STATS + (size_t)L * 4 * 2048;
        dim3 gatherg(MN / 8, O / 64);    // channel-split; gridDim.x % 8 == 0 keeps XCD pin
        edge_gather_kernel<<<gatherg, 256, 0, stream>>>(ws + HHOFF, idx, v8, enc_g[L],
                ws + HMAXO, ws + HMINO, statsL, O);
        float* scl = ws + SCALEO + (size_t)L * 1024;
        float* shf = ws + SHIFTO + (size_t)L * 1024;
        bn_params_kernel<<<(O + 255)/256, 256, 0, stream>>>(statsL, nvalid, enc_g[L], enc_b[L], scl, shf, O);
        edge_finalize_kernel<<<(int)(((size_t)MN * O) / 256), 256, 0, stream>>>(
            ws + HMAXO, ws + HMINO, ok8, scl, shf, xcatb, O, outoff[L]);
    }

    // dense bf16 layers: GEMM writes RAW output + fused masked stats; BN+lrelu of that
    // output is fused into the NEXT GEMM's A staging (scale/shift ready after bn_params).
    unsigned short* yemb1b = (unsigned short*)(ws + HMAXO);
    float* yemb2 = ws + HMINO;
    float* yout  = ws + HHOFF;

    float* scl4 = ws + SCALEO + 4 * 1024, *shf4 = ws + SHIFTO + 4 * 1024;
    float* scl5 = ws + SCALEO + 5 * 1024, *shf5 = ws + SHIFTO + 5 * 1024;
    float* scl6 = ws + SCALEO + 6 * 1024, *shf6 = ws + SHIFTO + 6 * 1024;

    // last: raw output ylb + stats
    {
        float* statsL = ws + STATS + (size_t)4 * 4 * 2048;
        dim3 gg(MN / 128, 1024 / 128);
        gemm_bf16_mfma<true, true, false><<<gg, 256, 0, stream>>>(xcatb, wlastb, ylb, nullptr, 512, CAT_C, 1024,
                ok8, statsL, nullptr, nullptr);
        bn_params_kernel<<<4, 256, 0, stream>>>(statsL, n_ok, last_g, last_b, scl4, shf4, 1024);
    }
    // emb1: A = bn_lrelu(ylb) fused via AFFA; raw output yemb1b + stats
    {
        float* statsL = ws + STATS + (size_t)5 * 4 * 2048;
        dim3 gg(MN / 128, 512 / 128);
        gemm_bf16_mfma<true, true, true><<<gg, 256, 0, stream>>>(ylb, wemb1b, yemb1b, emb_bi1, 1024, 1024, 512,
                ok8, statsL, scl4, shf4);
        bn_params_kernel<<<2, 256, 0, stream>>>(statsL, n_ok, emb_g1, emb_b1, scl5, shf5, 512);
    }
    // emb2: A = bn_lrelu(yemb1b) fused; raw f32 output yemb2 + stats
    {
        float* statsL = ws + STATS + (size_t)6 * 4 * 2048;
        dim3 gg(MN / 128, 128 / 128);
        gemm_bf16_mfma<false, true, true><<<gg, 256, 0, stream>>>(yemb1b, wemb2b, yemb2, emb_bi2, 512, 512, 128,
                ok8, statsL, scl5, shf5);
        bn_params_kernel<<<1, 256, 0, stream>>>(statsL, n_ok, emb_g2, emb_b2, scl6, shf6, 128);
    }
    // out layer (f32): X = bn_lrelu(yemb2) fused into staging; then transpose
    {
        dim3 gg(MN / 64, 1);
        gemm_f32<<<gg, 256, 0, stream>>>(yemb2, out_w, yout, out_bias, MN, 128, 32, 128, 32, scl6, shf6);
        transpose_out_kernel<<<(B_ * 32 * N_) / 256, 256, 0, stream>>>(yout, (float*)d_out);
    }
}

// Round 13
// 552.925 us; speedup vs baseline: 1.2691x; 1.2691x over previous
//
#include <hip/hip_runtime.h>
#include <hip/hip_bf16.h>
#include <cstdint>
#include <cstddef>

// ---------------- problem constants (fixed by setup_inputs) ----------------
constexpr int B_  = 8;
constexpr int N_  = 2048;
constexpr int KNB = 20;
constexpr int MN  = B_ * N_;        // 16384 points
constexpr int CAT_C = 512;          // concat channels 64+64+128+256
constexpr float EPS = 1e-5f;

typedef __attribute__((ext_vector_type(8))) short bf16x8;
typedef __attribute__((ext_vector_type(4))) float f32x4;

// ---------------- workspace layout (units: floats) ----------------
constexpr size_t alignup64(size_t x){ return (x + 63) & ~size_t(63); }
constexpr size_t STATS   = 0;                          // 7 layers * 4 replicas * 2048 (S1@+0, S2@+1024)
constexpr size_t NSTATS  = size_t(7) * 4 * 2048;       // 57344
constexpr size_t MISC    = STATS + NSTATS;             // [0]=nvalid [1]=n_ok [2]=flag
constexpr size_t SCALEO  = alignup64(MISC + 16);
constexpr size_t SHIFTO  = SCALEO + 7 * 1024;
constexpr size_t CIDX    = alignup64(SHIFTO + 7 * 1024);          // MN*KNB ints (compacted valid idx)
constexpr size_t OK8     = alignup64(CIDX + size_t(MN) * KNB);    // MN bytes (valid count per point)
constexpr size_t WENC    = alignup64(OK8 + (MN + 3) / 4);
constexpr size_t WLAST   = WENC  + 32768;    // 1024x512 bf16
constexpr size_t WEMB1   = WLAST + 262144;   // 512x1024 bf16
constexpr size_t WEMB2   = WEMB1 + 262144;   // 128x512 bf16
constexpr size_t XT      = WEMB2 + 32768;
constexpr size_t XCATB   = alignup64(XT + size_t(MN) * 4);   // bf16 MN x 512
constexpr size_t HHOFF   = XCATB + size_t(MN) * 256;         // f32 MN x 512
constexpr size_t HMAXO   = HHOFF + size_t(MN) * 512;         // f32 MN x 256
constexpr size_t HMINO   = HMAXO + size_t(MN) * 256;         // f32 MN x 256
constexpr size_t YLB     = HMINO + size_t(MN) * 256;         // bf16 MN x 1024 (raw, pre-BN)
// aliases after enc phase: yemb1_bf = HMAXO (bf16 MNx512, raw), yemb2_f32 = HMINO (f32 MNx128, raw),
//                          yout_f32 = HHOFF (f32 MNx32).  Total ~122 MB.

__device__ inline float bf2f(unsigned short u){
    unsigned int x = ((unsigned int)u) << 16;
    return __builtin_bit_cast(float, x);
}
__device__ inline unsigned short f2bf(float f){
    __hip_bfloat16 h = __float2bfloat16(f);
    return __builtin_bit_cast(unsigned short, h);
}
__device__ inline unsigned int packbf(float a, float b){
    return (unsigned int)f2bf(a) | ((unsigned int)f2bf(b) << 16);
}
__device__ inline void gl16(const void* g, void* l){
    __builtin_amdgcn_global_load_lds(
        (const __attribute__((address_space(1))) void*)g,
        (__attribute__((address_space(3))) void*)l, 16, 0, 0);
}

// ---------------- small utility kernels ----------------

__global__ __launch_bounds__(256) void detect_valid_kernel(const unsigned char* __restrict__ v, int* __restrict__ flag){
    __shared__ int f;
    if (threadIdx.x == 0) f = 1;
    __syncthreads();
    int ok = 1;
    #pragma unroll
    for (int it = 0; it < 4; ++it){
        int g = threadIdx.x + it * 256;
        unsigned char b0 = v[4*g], b1 = v[4*g+1], b2 = v[4*g+2], b3 = v[4*g+3];
        if ((b1 | b2 | b3) != 0 || b0 > 1) ok = 0;
    }
    if (!ok) atomicAnd(&f, 0);
    __syncthreads();
    if (threadIdx.x == 0) *flag = f;
}

// Fused: decode valid, STABLE-compact the valid neighbor indices into ci, write cnt -> ok,
// accumulate nvalid & n_ok. Compaction preserves order => downstream sums bitwise identical.
__global__ __launch_bounds__(256) void expand_ok_kernel(const void* __restrict__ vin,
        const int* __restrict__ idx, int* __restrict__ ci, unsigned char* __restrict__ ok,
        float* __restrict__ nvalid, float* __restrict__ n_ok, const int* __restrict__ flag){
    const int p = blockIdx.x * 256 + threadIdx.x;   // MN exact multiple of 256
    int jj[KNB];
    const int4* ip4 = (const int4*)(idx + (size_t)p * KNB);
    #pragma unroll
    for (int q = 0; q < 5; ++q){
        int4 iv = ip4[q];
        jj[q*4+0] = iv.x; jj[q*4+1] = iv.y; jj[q*4+2] = iv.z; jj[q*4+3] = iv.w;
    }
    bool val[KNB];
    if (*flag){
        const int* vi = ((const int*)vin) + (size_t)p * KNB;
        #pragma unroll
        for (int k = 0; k < KNB; ++k) val[k] = vi[k] != 0;
    } else {
        const unsigned char* vb = ((const unsigned char*)vin) + (size_t)p * KNB;
        #pragma unroll
        for (int k = 0; k < KNB; ++k) val[k] = vb[k] != 0;
    }
    int cnt = 0;
    int* dst = ci + (size_t)p * KNB;
    #pragma unroll
    for (int k = 0; k < KNB; ++k){
        if (val[k]) dst[cnt++] = jj[k];
    }
    ok[p] = (unsigned char)cnt;
    float fc = (float)cnt;
    #pragma unroll
    for (int o = 32; o > 0; o >>= 1) fc += __shfl_down(fc, o);
    unsigned long long m = __ballot(cnt != 0);
    if ((threadIdx.x & 63) == 0){
        if (fc > 0.f) unsafeAtomicAdd(nvalid, fc);
        if (m)        unsafeAtomicAdd(n_ok, (float)__popcll(m));
    }
}

// x (B,3,N) -> xT (B*N, 4) row-major (pad 4th with 0)
__global__ __launch_bounds__(256) void transpose_x_kernel(const float* __restrict__ x, float* __restrict__ xt){
    int i = blockIdx.x * 256 + threadIdx.x;
    if (i >= MN) return;
    int b = i / N_, n = i % N_;
    float4 v;
    v.x = x[(size_t)(b*3 + 0) * N_ + n];
    v.y = x[(size_t)(b*3 + 1) * N_ + n];
    v.z = x[(size_t)(b*3 + 2) * N_ + n];
    v.w = 0.f;
    ((float4*)xt)[i] = v;
}

// W (O,2C) -> Wcomb (2O,C) f32
__global__ __launch_bounds__(256) void build_wcomb_f32_kernel(const float* __restrict__ W, float* __restrict__ wc,
        int O, int C){
    int i = blockIdx.x * 256 + threadIdx.x;
    if (i >= 2 * O * C) return;
    int r = i / C, c = i % C;
    float v;
    if (r < O) v = W[(size_t)r * (2*C) + c];
    else       v = W[(size_t)(r-O) * (2*C) + C + c] - W[(size_t)(r-O) * (2*C) + c];
    wc[i] = v;
}

// same but emits bf16
__global__ __launch_bounds__(256) void build_wcomb_bf16_kernel(const float* __restrict__ W, unsigned short* __restrict__ wc,
        int O, int C){
    int i = blockIdx.x * 256 + threadIdx.x;
    if (i >= 2 * O * C) return;
    int r = i / C, c = i % C;
    float v;
    if (r < O) v = W[(size_t)r * (2*C) + c];
    else       v = W[(size_t)(r-O) * (2*C) + C + c] - W[(size_t)(r-O) * (2*C) + c];
    wc[i] = f2bf(v);
}

// all three dense-weight conversions in one kernel (f32 -> bf16, float4 granules)
__global__ __launch_bounds__(256) void convert3_bf16_kernel(
        const float* __restrict__ a, const float* __restrict__ b, const float* __restrict__ c,
        unsigned short* __restrict__ wa, unsigned short* __restrict__ wb, unsigned short* __restrict__ wcc){
    int i = blockIdx.x * 256 + threadIdx.x;
    if (i >= 278528) return;
    const float* src; unsigned short* dst; int off;
    if (i < 131072)      { src = a; dst = wa;  off = i; }
    else if (i < 262144) { src = b; dst = wb;  off = i - 131072; }
    else                 { src = c; dst = wcc; off = i - 262144; }
    float4 v = ((const float4*)src)[off];
    ushort4 o;
    o.x = f2bf(v.x); o.y = f2bf(v.y); o.z = f2bf(v.z); o.w = f2bf(v.w);
    ((ushort4*)dst)[off] = o;
}

// ---------------- f32 tiled GEMM (enc1 K=3; out layer O=32 with optional fused BN+lrelu on X) ----------------
__global__ __launch_bounds__(256) void gemm_f32(
        const float* __restrict__ X, const float* __restrict__ W,
        float* __restrict__ Y, const float* __restrict__ bias,
        int M, int K, int O, int lda, int ldy,
        const float* __restrict__ scX, const float* __restrict__ shX)
{
    __shared__ float Xs[16][68];
    __shared__ float Ws[16][68];
    const int tid = threadIdx.x;
    const int tx = tid & 15, ty = tid >> 4;
    const int m0 = blockIdx.x * 64, o0 = blockIdx.y * 64;
    float acc[4][4] = {};
    for (int k0 = 0; k0 < K; k0 += 16){
        #pragma unroll
        for (int i = 0; i < 4; ++i){
            int e = tid + i * 256;
            int r = e >> 4, c = e & 15;
            float xv = 0.f, wv = 0.f;
            if (k0 + c < K){
                xv = X[(size_t)(m0 + r) * lda + k0 + c];
                if (scX){
                    xv = xv * scX[k0 + c] + shX[k0 + c];
                    xv = (xv > 0.f) ? xv : 0.2f * xv;
                }
                if (o0 + r < O) wv = W[(size_t)(o0 + r) * K + k0 + c];
            }
            Xs[c][r] = xv;
            Ws[c][r] = wv;
        }
        __syncthreads();
        #pragma unroll
        for (int kk = 0; kk < 16; ++kk){
            const float4 a4 = *(const float4*)(&Xs[kk][ty * 4]);
            const float4 b4 = *(const float4*)(&Ws[kk][tx * 4]);
            const float a[4] = {a4.x, a4.y, a4.z, a4.w};
            const float b[4] = {b4.x, b4.y, b4.z, b4.w};
            #pragma unroll
            for (int i = 0; i < 4; ++i)
                #pragma unroll
                for (int j = 0; j < 4; ++j)
                    acc[i][j] = fmaf(a[i], b[j], acc[i][j]);
        }
        __syncthreads();
    }
    #pragma unroll
    for (int i = 0; i < 4; ++i){
        int m = m0 + ty * 4 + i;
        int o = o0 + tx * 4;
        if (o < O){
            float4 v;
            v.x = acc[i][0]; v.y = acc[i][1]; v.z = acc[i][2]; v.w = acc[i][3];
            if (bias){
                v.x += bias[o]; v.y += bias[o+1]; v.z += bias[o+2]; v.w += bias[o+3];
            }
            *(float4*)(&Y[(size_t)m * ldy + o]) = v;
        }
    }
}

// ---------------- bf16 MFMA GEMM: Y(M,O) = X(M,K)bf16 @ W(O,K)bf16^T (+bias) ----------------
// m97 structure: 128x128 tile, BK=64, 4 waves 2x2, global_load_lds w=16, XOR chunk-swizzle.
// STATSF: fuse masked per-channel sum/sumsq accumulation (over ok rows) into the epilogue.
// AFFA: fuse per-K-channel affine+lrelu (BN of the PREVIOUS layer) into A staging.
template<bool OBF16, bool STATSF, bool AFFA>
__global__ __launch_bounds__(256) void gemm_bf16_mfma(
        const unsigned short* __restrict__ Xg, const unsigned short* __restrict__ Wg,
        void* __restrict__ Yv, const float* __restrict__ bias,
        int K, int ldx, int ldy,
        const unsigned char* __restrict__ ok, float* __restrict__ statsL,
        const float* __restrict__ scA, const float* __restrict__ shA)
{
    __shared__ unsigned short As[128 * 64];
    __shared__ unsigned short Bs[128 * 64];
    const int t = threadIdx.x;
    const int lane = t & 63;
    const int w = t >> 6;
    const int wr = w >> 1, wc = w & 1;
    const int m0 = blockIdx.x * 128;
    const int o0 = blockIdx.y * 128;

    f32x4 acc[4][4] = {};

    for (int k0 = 0; k0 < K; k0 += 64){
        #pragma unroll
        for (int i = 0; i < 4; ++i){
            int e = i * 256 + t;                 // chunk id (16B each)
            int row = e >> 3;                    // 0..127
            int c = (e & 7) ^ (row & 7);         // pre-swizzled SOURCE chunk (m173 pattern)
            int kk = k0 + c * 8;
            if constexpr (AFFA){
                uint4 a = *(const uint4*)(Xg + (size_t)(m0 + row) * ldx + kk);
                float4 s0 = *(const float4*)&scA[kk], s1 = *(const float4*)&scA[kk + 4];
                float4 h0 = *(const float4*)&shA[kk], h1 = *(const float4*)&shA[kk + 4];
                const float sc[8] = {s0.x,s0.y,s0.z,s0.w, s1.x,s1.y,s1.z,s1.w};
                const float sh[8] = {h0.x,h0.y,h0.z,h0.w, h1.x,h1.y,h1.z,h1.w};
                unsigned int wds[4] = {a.x, a.y, a.z, a.w};
                unsigned int ov[4];
                #pragma unroll
                for (int q = 0; q < 4; ++q){
                    float f0 = bf2f((unsigned short)(wds[q] & 0xffffu)) * sc[2*q]   + sh[2*q];
                    float f1 = bf2f((unsigned short)(wds[q] >> 16))     * sc[2*q+1] + sh[2*q+1];
                    f0 = (f0 > 0.f) ? f0 : 0.2f * f0;
                    f1 = (f1 > 0.f) ? f1 : 0.2f * f1;
                    ov[q] = packbf(f0, f1);
                }
                uint4 o4 = {ov[0], ov[1], ov[2], ov[3]};
                *(uint4*)&As[(size_t)e * 8] = o4;   // same linear LDS dest as gl16
            } else {
                gl16(Xg + (size_t)(m0 + row) * ldx + kk, &As[(size_t)e * 8]);
            }
            gl16(Wg + (size_t)(o0 + row) * K + kk, &Bs[(size_t)e * 8]);
        }
        __syncthreads();
        const int kq = lane >> 4;                // 0..3
        #pragma unroll
        for (int ks = 0; ks < 2; ++ks){
            bf16x8 a[4], b[4];
            #pragma unroll
            for (int mi = 0; mi < 4; ++mi){
                int r = wr * 64 + mi * 16 + (lane & 15);
                int ch = (ks * 4 + kq) ^ (r & 7);
                a[mi] = *(const bf16x8*)&As[r * 64 + ch * 8];
            }
            #pragma unroll
            for (int ni = 0; ni < 4; ++ni){
                int r = wc * 64 + ni * 16 + (lane & 15);
                int ch = (ks * 4 + kq) ^ (r & 7);
                b[ni] = *(const bf16x8*)&Bs[r * 64 + ch * 8];
            }
            #pragma unroll
            for (int mi = 0; mi < 4; ++mi)
                #pragma unroll
                for (int ni = 0; ni < 4; ++ni)
                    acc[mi][ni] = __builtin_amdgcn_mfma_f32_16x16x32_bf16(a[mi], b[ni], acc[mi][ni], 0, 0, 0);
        }
        __syncthreads();
    }

    // C/D layout (m89-verified): col = lane&15, row = (lane>>4)*4 + reg
    float s1l[4] = {}, s2l[4] = {};
    float bi[4];
    #pragma unroll
    for (int ni = 0; ni < 4; ++ni)
        bi[ni] = bias ? bias[o0 + wc * 64 + ni * 16 + (lane & 15)] : 0.f;

    #pragma unroll
    for (int mi = 0; mi < 4; ++mi){
        const int mbase = m0 + wr * 64 + mi * 16 + (lane >> 4) * 4;
        uchar4 okv = {1,1,1,1};
        if constexpr (STATSF) okv = *(const uchar4*)(ok + mbase);
        const unsigned char okarr[4] = {okv.x, okv.y, okv.z, okv.w};
        #pragma unroll
        for (int j = 0; j < 4; ++j){
            const int m = mbase + j;
            #pragma unroll
            for (int ni = 0; ni < 4; ++ni){
                int o = o0 + wc * 64 + ni * 16 + (lane & 15);
                float v = acc[mi][ni][j] + bi[ni];
                if constexpr (STATSF){
                    if (okarr[j]){ s1l[ni] += v; s2l[ni] += v * v; }
                }
                if constexpr (OBF16)
                    ((unsigned short*)Yv)[(size_t)m * ldy + o] = f2bf(v);
                else
                    ((float*)Yv)[(size_t)m * ldy + o] = v;
            }
        }
    }

    if constexpr (STATSF){
        #pragma unroll
        for (int ni = 0; ni < 4; ++ni){
            s1l[ni] += __shfl_xor(s1l[ni], 16); s1l[ni] += __shfl_xor(s1l[ni], 32);
            s2l[ni] += __shfl_xor(s2l[ni], 16); s2l[ni] += __shfl_xor(s2l[ni], 32);
        }
        if ((lane >> 4) == 0){
            float* S = statsL + (size_t)((blockIdx.x + blockIdx.y) & 3) * 2048;
            #pragma unroll
            for (int ni = 0; ni < 4; ++ni){
                int o = o0 + wc * 64 + ni * 16 + lane;
                unsafeAtomicAdd(&S[o],        s1l[ni]);
                unsafeAtomicAdd(&S[1024 + o], s2l[ni]);
            }
        }
    }
}

// ---------------- edge gather: round-11 shape + compacted valid list ----------------
// lane=channel, 2 pts/wave, XCD-pinned batches, NT stores. Loop runs cnt (avg ~10)
// iterations over pre-compacted indices: no masks, no wasted loads. Bitwise identical
// (stable compaction preserves accumulation order; skipped terms were exact identities).
// hmin path only when some gamma<0.
template<int T>  // T = O/64
__global__ __launch_bounds__(256) void edge_gather_kernel(
        const float* __restrict__ HHp, const int* __restrict__ ci,
        const unsigned char* __restrict__ okc, const float* __restrict__ g,
        float* __restrict__ hmaxo, float* __restrict__ hmino,
        float* __restrict__ statsL)
{
    constexpr int O = 64 * T, TWO2 = 2 * O;
    const int bid  = blockIdx.x;                 // MN/8 blocks
    const int wv   = threadIdx.x >> 6;
    const int lane = threadIdx.x & 63;
    const int bat  = bid & 7;                    // batch == XCD (round-robin dispatch)
    const int chunk = bid >> 3;
    const int base = bat << 11;
    const int p0   = base + chunk * 8 + wv * 2;

    bool ln = false;
    #pragma unroll
    for (int t = 0; t < T; ++t) if (g[lane + 64 * t] < 0.f) ln = true;
    const bool needmin = (__ballot(ln) != 0ull);

    float s1[T] = {}, s2[T] = {};
    #pragma unroll
    for (int pi = 0; pi < 2; ++pi){
        const int p = p0 + pi;
        const int cnt = okc[p];
        int jj[KNB];
        const int4* ip4 = (const int4*)(ci + (size_t)p * KNB);
        #pragma unroll
        for (int q = 0; q < 5; ++q){
            int4 iv = ip4[q];
            jj[q*4+0] = iv.x; jj[q*4+1] = iv.y; jj[q*4+2] = iv.z; jj[q*4+3] = iv.w;
        }
        float hc[T], hmax[T], hmin[T];
        #pragma unroll
        for (int t = 0; t < T; ++t){
            hc[t] = HHp[(size_t)p * TWO2 + O + lane + 64 * t];
            hmax[t] = -INFINITY; hmin[t] = INFINITY;
        }
        if (needmin){
            int k = 0;
            for (; k + 4 <= cnt; k += 4){
                #pragma unroll
                for (int u = 0; u < 4; ++u){
                    const float* row = HHp + (size_t)(base + jj[k + u]) * TWO2 + lane;
                    #pragma unroll
                    for (int t = 0; t < T; ++t){
                        float h = row[64 * t] + hc[t];
                        s1[t] += h; s2[t] += h * h;
                        hmax[t] = fmaxf(hmax[t], h);
                        hmin[t] = fminf(hmin[t], h);
                    }
                }
            }
            for (; k < cnt; ++k){
                const float* row = HHp + (size_t)(base + jj[k]) * TWO2 + lane;
                #pragma unroll
                for (int t = 0; t < T; ++t){
                    float h = row[64 * t] + hc[t];
                    s1[t] += h; s2[t] += h * h;
                    hmax[t] = fmaxf(hmax[t], h);
                    hmin[t] = fminf(hmin[t], h);
                }
            }
        } else {
            int k = 0;
            for (; k + 4 <= cnt; k += 4){
                #pragma unroll
                for (int u = 0; u < 4; ++u){
                    const float* row = HHp + (size_t)(base + jj[k + u]) * TWO2 + lane;
                    #pragma unroll
                    for (int t = 0; t < T; ++t){
                        float h = row[64 * t] + hc[t];
                        s1[t] += h; s2[t] += h * h;
                        hmax[t] = fmaxf(hmax[t], h);
                    }
                }
            }
            for (; k < cnt; ++k){
                const float* row = HHp + (size_t)(base + jj[k]) * TWO2 + lane;
                #pragma unroll
                for (int t = 0; t < T; ++t){
                    float h = row[64 * t] + hc[t];
                    s1[t] += h; s2[t] += h * h;
                    hmax[t] = fmaxf(hmax[t], h);
                }
            }
        }
        #pragma unroll
        for (int t = 0; t < T; ++t)
            __builtin_nontemporal_store(hmax[t], &hmaxo[(size_t)p * O + lane + 64 * t]);
        if (needmin){
            #pragma unroll
            for (int t = 0; t < T; ++t)
                __builtin_nontemporal_store(hmin[t], &hmino[(size_t)p * O + lane + 64 * t]);
        }
    }
    float* S1 = statsL + (size_t)(wv & 3) * 2048;
    float* S2 = S1 + 1024;
    #pragma unroll
    for (int t = 0; t < T; ++t){
        unsafeAtomicAdd(&S1[lane + 64 * t], s1[t]);
        unsafeAtomicAdd(&S2[lane + 64 * t], s2[t]);
    }
}

// ---------------- BN parameter computation ----------------
__global__ void bn_params_kernel(const float* __restrict__ statsL, const float* __restrict__ cnt,
        const float* __restrict__ g, const float* __restrict__ bta,
        float* __restrict__ scale, float* __restrict__ shift, int O)
{
    int o = blockIdx.x * 256 + threadIdx.x;
    if (o >= O) return;
    float s1 = 0.f, s2 = 0.f;
    #pragma unroll
    for (int r = 0; r < 4; ++r){
        s1 += statsL[(size_t)r * 2048 + o];
        s2 += statsL[(size_t)r * 2048 + 1024 + o];
    }
    float n   = fmaxf(*cnt, 1.0f);
    float mu  = s1 / n;
    float var = fmaxf(s2 / n - mu * mu, 0.f);
    float sc  = g[o] * rsqrtf(var + EPS);
    scale[o] = sc;
    shift[o] = bta[o] - mu * sc;
}

// ---------------- edge finalize: affine+lrelu on masked max -> bf16 concat buffer ----------------
__global__ __launch_bounds__(256) void edge_finalize_kernel(
        const float* __restrict__ hmaxo, const float* __restrict__ hmino,
        const unsigned char* __restrict__ ok,
        const float* __restrict__ scale, const float* __restrict__ shift,
        unsigned short* __restrict__ xcat, int O, int chanoff)
{
    size_t i = (size_t)blockIdx.x * 256 + threadIdx.x;
    size_t p = i / (size_t)O;
    int o = (int)(i - p * (size_t)O);
    float v = 0.f;
    if (ok[p]){
        float sc = scale[o];
        float h;
        if (sc >= 0.f) h = hmaxo[i]; else h = hmino[i];
        v = h * sc + shift[o];
        v = (v > 0.f) ? v : 0.2f * v;
    }
    xcat[p * CAT_C + chanoff + o] = f2bf(v);
}

// ---------------- final transpose (B,N,32) -> (B,32,N) ----------------
__global__ __launch_bounds__(256) void transpose_out_kernel(const float* __restrict__ Y, float* __restrict__ out){
    int i = blockIdx.x * 256 + threadIdx.x;
    int n = i & (N_ - 1);
    int rest = i >> 11;
    int o = rest & 31;
    int b = rest >> 5;
    out[i] = Y[((((size_t)b * N_) + n) << 5) + o];
}

// ---------------- host side ----------------
extern "C" void kernel_launch(void* const* d_in, const int* in_sizes, int n_in,
                              void* d_out, int out_size, void* d_ws, size_t ws_size,
                              hipStream_t stream)
{
    const float* x        = (const float*)d_in[0];
    const int*   idx      = (const int*)  d_in[1];
    const void*  valid_rw = d_in[2];
    const float* enc_w[4] = {(const float*)d_in[3], (const float*)d_in[6], (const float*)d_in[9],  (const float*)d_in[12]};
    const float* enc_g[4] = {(const float*)d_in[4], (const float*)d_in[7], (const float*)d_in[10], (const float*)d_in[13]};
    const float* enc_b[4] = {(const float*)d_in[5], (const float*)d_in[8], (const float*)d_in[11], (const float*)d_in[14]};
    const float* last_w   = (const float*)d_in[15];
    const float* last_g   = (const float*)d_in[16];
    const float* last_b   = (const float*)d_in[17];
    const float* emb_w1   = (const float*)d_in[18];
    const float* emb_bi1  = (const float*)d_in[19];
    const float* emb_g1   = (const float*)d_in[20];
    const float* emb_b1   = (const float*)d_in[21];
    const float* emb_w2   = (const float*)d_in[22];
    const float* emb_bi2  = (const float*)d_in[23];
    const float* emb_g2   = (const float*)d_in[24];
    const float* emb_b2   = (const float*)d_in[25];
    const float* out_w    = (const float*)d_in[26];
    const float* out_bias = (const float*)d_in[27];

    float* ws = (float*)d_ws;
    int*   ci   = (int*)(ws + CIDX);
    unsigned char* ok8  = (unsigned char*)(ws + OK8);
    unsigned short* xcatb = (unsigned short*)(ws + XCATB);
    unsigned short* ylb   = (unsigned short*)(ws + YLB);
    unsigned short* wlastb = (unsigned short*)(ws + WLAST);
    unsigned short* wemb1b = (unsigned short*)(ws + WEMB1);
    unsigned short* wemb2b = (unsigned short*)(ws + WEMB2);
    float* nvalid = ws + MISC + 0;
    float* n_ok   = ws + MISC + 1;
    int*   flag   = (int*)(ws + MISC + 2);

    hipMemsetAsync(d_ws, 0, (MISC + 16) * sizeof(float), stream);

    detect_valid_kernel<<<1, 256, 0, stream>>>((const unsigned char*)valid_rw, flag);
    expand_ok_kernel<<<MN / 256, 256, 0, stream>>>(valid_rw, idx, ci, ok8, nvalid, n_ok, flag);
    transpose_x_kernel<<<MN / 256, 256, 0, stream>>>(x, ws + XT);
    convert3_bf16_kernel<<<(278528 + 255) / 256, 256, 0, stream>>>(last_w, emb_w1, emb_w2, wlastb, wemb1b, wemb2b);

    const int Cs[4]     = {3, 64, 64, 128};
    const int Os[4]     = {64, 64, 128, 256};
    const int inoff[4]  = {0, 0, 64, 128};
    const int outoff[4] = {0, 64, 128, 256};

    for (int L = 0; L < 4; ++L){
        const int C = Cs[L], O = Os[L], TWO2 = 2 * O;
        if (L == 0){
            build_wcomb_f32_kernel<<<(2*O*C + 255)/256, 256, 0, stream>>>(enc_w[L], ws + WENC, O, C);
            dim3 gg(MN / 64, TWO2 / 64);
            gemm_f32<<<gg, 256, 0, stream>>>(ws + XT, ws + WENC, ws + HHOFF, nullptr, MN, C, TWO2, 4, TWO2, nullptr, nullptr);
        } else {
            build_wcomb_bf16_kernel<<<(2*O*C + 255)/256, 256, 0, stream>>>(enc_w[L], (unsigned short*)(ws + WENC), O, C);
            dim3 gg(MN / 128, TWO2 / 128);
            gemm_bf16_mfma<false, false, false><<<gg, 256, 0, stream>>>(xcatb + inoff[L], (unsigned short*)(ws + WENC),
                    ws + HHOFF, nullptr, C, CAT_C, TWO2, nullptr, nullptr, nullptr, nullptr);
        }
        float* statsL = ws + STATS + (size_t)L * 4 * 2048;
        const int gather_blocks = MN / 8;   // 8 points/block, batch pinned to XCD
        switch (O / 64){
            case 1: edge_gather_kernel<1><<<gather_blocks, 256, 0, stream>>>(ws + HHOFF, ci, ok8, enc_g[L], ws + HMAXO, ws + HMINO, statsL); break;
            case 2: edge_gather_kernel<2><<<gather_blocks, 256, 0, stream>>>(ws + HHOFF, ci, ok8, enc_g[L], ws + HMAXO, ws + HMINO, statsL); break;
            case 4: edge_gather_kernel<4><<<gather_blocks, 256, 0, stream>>>(ws + HHOFF, ci, ok8, enc_g[L], ws + HMAXO, ws + HMINO, statsL); break;
        }
        float* scl = ws + SCALEO + (size_t)L * 1024;
        float* shf = ws + SHIFTO + (size_t)L * 1024;
        bn_params_kernel<<<(O + 255)/256, 256, 0, stream>>>(statsL, nvalid, enc_g[L], enc_b[L], scl, shf, O);
        edge_finalize_kernel<<<(int)(((size_t)MN * O) / 256), 256, 0, stream>>>(
            ws + HMAXO, ws + HMINO, ok8, scl, shf, xcatb, O, outoff[L]);
    }

    // dense bf16 layers: GEMM writes RAW output + fused masked stats; BN+lrelu of that
    // output is fused into the NEXT GEMM's A staging (scale/shift ready after bn_params).
    unsigned short* yemb1b = (unsigned short*)(ws + HMAXO);
    float* yemb2 = ws + HMINO;
    float* yout  = ws + HHOFF;

    float* scl4 = ws + SCALEO + 4 * 1024, *shf4 = ws + SHIFTO + 4 * 1024;
    float* scl5 = ws + SCALEO + 5 * 1024, *shf5 = ws + SHIFTO + 5 * 1024;
    float* scl6 = ws + SCALEO + 6 * 1024, *shf6 = ws + SHIFTO + 6 * 1024;

    // last: raw output ylb + stats
    {
        float* statsL = ws + STATS + (size_t)4 * 4 * 2048;
        dim3 gg(MN / 128, 1024 / 128);
        gemm_bf16_mfma<true, true, false><<<gg, 256, 0, stream>>>(xcatb, wlastb, ylb, nullptr, 512, CAT_C, 1024,
                ok8, statsL, nullptr, nullptr);
        bn_params_kernel<<<4, 256, 0, stream>>>(statsL, n_ok, last_g, last_b, scl4, shf4, 1024);
    }
    // emb1: A = bn_lrelu(ylb) fused via AFFA; raw output yemb1b + stats
    {
        float* statsL = ws + STATS + (size_t)5 * 4 * 2048;
        dim3 gg(MN / 128, 512 / 128);
        gemm_bf16_mfma<true, true, true><<<gg, 256, 0, stream>>>(ylb, wemb1b, yemb1b, emb_bi1, 1024, 1024, 512,
                ok8, statsL, scl4, shf4);
        bn_params_kernel<<<2, 256, 0, stream>>>(statsL, n_ok, emb_g1, emb_b1, scl5, shf5, 512);
    }
    // emb2: A = bn_lrelu(yemb1b) fused; raw f32 output yemb2 + stats
    {
        float* statsL = ws + STATS + (size_t)6 * 4 * 2048;
        dim3 gg(MN / 128, 128 / 128);
        gemm_bf16_mfma<false, true, true><<<gg, 256, 0, stream>>>(yemb1b, wemb2b, yemb2, emb_bi2, 512, 512, 128,
                ok8, statsL, scl5, shf5);
        bn_params_kernel<<<1, 256, 0, stream>>>(statsL, n_ok, emb_g2, emb_b2, scl6, shf6, 128);
    }
    // out layer (f32): X = bn_lrelu(yemb2) fused into staging; then transpose
    {
        dim3 gg(MN / 64, 1);
        gemm_f32<<<gg, 256, 0, stream>>>(yemb2, out_w, yout, out_bias, MN, 128, 32, 128, 32, scl6, shf6);
        transpose_out_kernel<<<(B_ * 32 * N_) / 256, 256, 0, stream>>>(yout, (float*)d_out);
    }
}

// Round 14
// 393.793 us; speedup vs baseline: 1.7819x; 1.4041x over previous
//
#include <hip/hip_runtime.h>
#include <hip/hip_bf16.h>
#include <cstdint>
#include <cstddef>

// ---------------- problem constants (fixed by setup_inputs) ----------------
constexpr int B_  = 8;
constexpr int N_  = 2048;
constexpr int KNB = 20;
constexpr int MN  = B_ * N_;        // 16384 points
constexpr int CAT_C = 512;          // concat channels 64+64+128+256
constexpr float EPS = 1e-5f;

typedef __attribute__((ext_vector_type(8))) short bf16x8;
typedef __attribute__((ext_vector_type(4))) float f32x4;

// ---------------- workspace layout (units: floats) ----------------
constexpr size_t alignup64(size_t x){ return (x + 63) & ~size_t(63); }
constexpr size_t STATS   = 0;                          // 7 layers * 8 replicas * 2048 (S1@+0, S2@+1024)
constexpr size_t NSTATS  = size_t(7) * 8 * 2048;       // 114688
constexpr size_t MISC    = STATS + NSTATS;             // [0]=nvalid [1]=n_ok [2]=flag
constexpr size_t SCALEO  = alignup64(MISC + 16);
constexpr size_t SHIFTO  = SCALEO + 7 * 1024;
constexpr size_t CIDX    = alignup64(SHIFTO + 7 * 1024);          // MN*KNB ints (compacted valid idx)
constexpr size_t OK8     = alignup64(CIDX + size_t(MN) * KNB);    // MN bytes (valid count per point)
constexpr size_t WENC    = alignup64(OK8 + (MN + 3) / 4);
constexpr size_t WLAST   = WENC  + 32768;    // 1024x512 bf16
constexpr size_t WEMB1   = WLAST + 262144;   // 512x1024 bf16
constexpr size_t WEMB2   = WEMB1 + 262144;   // 128x512 bf16
constexpr size_t XT      = WEMB2 + 32768;
constexpr size_t XCATB   = alignup64(XT + size_t(MN) * 4);   // bf16 MN x 512
constexpr size_t HHOFF   = XCATB + size_t(MN) * 256;         // f32 MN x 512
constexpr size_t HMAXO   = HHOFF + size_t(MN) * 512;         // f32 MN x 256
constexpr size_t HMINO   = HMAXO + size_t(MN) * 256;         // f32 MN x 256
constexpr size_t YLB     = HMINO + size_t(MN) * 256;         // bf16 MN x 1024 (raw, pre-BN)
// aliases after enc phase: yemb1_bf = HMAXO (bf16 MNx512, raw), yemb2_f32 = HMINO (f32 MNx128, raw),
//                          yout_f32 = HHOFF (f32 MNx32).  Total ~122 MB.

__device__ inline float bf2f(unsigned short u){
    unsigned int x = ((unsigned int)u) << 16;
    return __builtin_bit_cast(float, x);
}
__device__ inline unsigned short f2bf(float f){
    __hip_bfloat16 h = __float2bfloat16(f);
    return __builtin_bit_cast(unsigned short, h);
}
__device__ inline unsigned int packbf(float a, float b){
    return (unsigned int)f2bf(a) | ((unsigned int)f2bf(b) << 16);
}
__device__ inline void gl16(const void* g, void* l){
    __builtin_amdgcn_global_load_lds(
        (const __attribute__((address_space(1))) void*)g,
        (__attribute__((address_space(3))) void*)l, 16, 0, 0);
}

// ---------------- small utility kernels ----------------

__global__ __launch_bounds__(256) void detect_valid_kernel(const unsigned char* __restrict__ v, int* __restrict__ flag){
    __shared__ int f;
    if (threadIdx.x == 0) f = 1;
    __syncthreads();
    int ok = 1;
    #pragma unroll
    for (int it = 0; it < 4; ++it){
        int g = threadIdx.x + it * 256;
        unsigned char b0 = v[4*g], b1 = v[4*g+1], b2 = v[4*g+2], b3 = v[4*g+3];
        if ((b1 | b2 | b3) != 0 || b0 > 1) ok = 0;
    }
    if (!ok) atomicAnd(&f, 0);
    __syncthreads();
    if (threadIdx.x == 0) *flag = f;
}

// Fused: decode valid, STABLE-compact the valid neighbor indices into ci, write cnt -> ok,
// accumulate nvalid & n_ok.
__global__ __launch_bounds__(256) void expand_ok_kernel(const void* __restrict__ vin,
        const int* __restrict__ idx, int* __restrict__ ci, unsigned char* __restrict__ ok,
        float* __restrict__ nvalid, float* __restrict__ n_ok, const int* __restrict__ flag){
    const int p = blockIdx.x * 256 + threadIdx.x;   // MN exact multiple of 256
    int jj[KNB];
    const int4* ip4 = (const int4*)(idx + (size_t)p * KNB);
    #pragma unroll
    for (int q = 0; q < 5; ++q){
        int4 iv = ip4[q];
        jj[q*4+0] = iv.x; jj[q*4+1] = iv.y; jj[q*4+2] = iv.z; jj[q*4+3] = iv.w;
    }
    bool val[KNB];
    if (*flag){
        const int* vi = ((const int*)vin) + (size_t)p * KNB;
        #pragma unroll
        for (int k = 0; k < KNB; ++k) val[k] = vi[k] != 0;
    } else {
        const unsigned char* vb = ((const unsigned char*)vin) + (size_t)p * KNB;
        #pragma unroll
        for (int k = 0; k < KNB; ++k) val[k] = vb[k] != 0;
    }
    int cnt = 0;
    int* dst = ci + (size_t)p * KNB;
    #pragma unroll
    for (int k = 0; k < KNB; ++k){
        if (val[k]) dst[cnt++] = jj[k];
    }
    ok[p] = (unsigned char)cnt;
    float fc = (float)cnt;
    #pragma unroll
    for (int o = 32; o > 0; o >>= 1) fc += __shfl_down(fc, o);
    unsigned long long m = __ballot(cnt != 0);
    if ((threadIdx.x & 63) == 0){
        if (fc > 0.f) unsafeAtomicAdd(nvalid, fc);
        if (m)        unsafeAtomicAdd(n_ok, (float)__popcll(m));
    }
}

// x (B,3,N) -> xT (B*N, 4) row-major (pad 4th with 0)
__global__ __launch_bounds__(256) void transpose_x_kernel(const float* __restrict__ x, float* __restrict__ xt){
    int i = blockIdx.x * 256 + threadIdx.x;
    if (i >= MN) return;
    int b = i / N_, n = i % N_;
    float4 v;
    v.x = x[(size_t)(b*3 + 0) * N_ + n];
    v.y = x[(size_t)(b*3 + 1) * N_ + n];
    v.z = x[(size_t)(b*3 + 2) * N_ + n];
    v.w = 0.f;
    ((float4*)xt)[i] = v;
}

// W (O,2C) -> Wcomb (2O,C) f32
__global__ __launch_bounds__(256) void build_wcomb_f32_kernel(const float* __restrict__ W, float* __restrict__ wc,
        int O, int C){
    int i = blockIdx.x * 256 + threadIdx.x;
    if (i >= 2 * O * C) return;
    int r = i / C, c = i % C;
    float v;
    if (r < O) v = W[(size_t)r * (2*C) + c];
    else       v = W[(size_t)(r-O) * (2*C) + C + c] - W[(size_t)(r-O) * (2*C) + c];
    wc[i] = v;
}

// same but emits bf16
__global__ __launch_bounds__(256) void build_wcomb_bf16_kernel(const float* __restrict__ W, unsigned short* __restrict__ wc,
        int O, int C){
    int i = blockIdx.x * 256 + threadIdx.x;
    if (i >= 2 * O * C) return;
    int r = i / C, c = i % C;
    float v;
    if (r < O) v = W[(size_t)r * (2*C) + c];
    else       v = W[(size_t)(r-O) * (2*C) + C + c] - W[(size_t)(r-O) * (2*C) + c];
    wc[i] = f2bf(v);
}

// all three dense-weight conversions in one kernel (f32 -> bf16, float4 granules)
__global__ __launch_bounds__(256) void convert3_bf16_kernel(
        const float* __restrict__ a, const float* __restrict__ b, const float* __restrict__ c,
        unsigned short* __restrict__ wa, unsigned short* __restrict__ wb, unsigned short* __restrict__ wcc){
    int i = blockIdx.x * 256 + threadIdx.x;
    if (i >= 278528) return;
    const float* src; unsigned short* dst; int off;
    if (i < 131072)      { src = a; dst = wa;  off = i; }
    else if (i < 262144) { src = b; dst = wb;  off = i - 131072; }
    else                 { src = c; dst = wcc; off = i - 262144; }
    float4 v = ((const float4*)src)[off];
    ushort4 o;
    o.x = f2bf(v.x); o.y = f2bf(v.y); o.z = f2bf(v.z); o.w = f2bf(v.w);
    ((ushort4*)dst)[off] = o;
}

// ---------------- f32 tiled GEMM (enc1 K=3; out layer O=32 with optional fused BN+lrelu on X) ----------------
__global__ __launch_bounds__(256) void gemm_f32(
        const float* __restrict__ X, const float* __restrict__ W,
        float* __restrict__ Y, const float* __restrict__ bias,
        int M, int K, int O, int lda, int ldy,
        const float* __restrict__ scX, const float* __restrict__ shX)
{
    __shared__ float Xs[16][68];
    __shared__ float Ws[16][68];
    const int tid = threadIdx.x;
    const int tx = tid & 15, ty = tid >> 4;
    const int m0 = blockIdx.x * 64, o0 = blockIdx.y * 64;
    float acc[4][4] = {};
    for (int k0 = 0; k0 < K; k0 += 16){
        #pragma unroll
        for (int i = 0; i < 4; ++i){
            int e = tid + i * 256;
            int r = e >> 4, c = e & 15;
            float xv = 0.f, wv = 0.f;
            if (k0 + c < K){
                xv = X[(size_t)(m0 + r) * lda + k0 + c];
                if (scX){
                    xv = xv * scX[k0 + c] + shX[k0 + c];
                    xv = (xv > 0.f) ? xv : 0.2f * xv;
                }
                if (o0 + r < O) wv = W[(size_t)(o0 + r) * K + k0 + c];
            }
            Xs[c][r] = xv;
            Ws[c][r] = wv;
        }
        __syncthreads();
        #pragma unroll
        for (int kk = 0; kk < 16; ++kk){
            const float4 a4 = *(const float4*)(&Xs[kk][ty * 4]);
            const float4 b4 = *(const float4*)(&Ws[kk][tx * 4]);
            const float a[4] = {a4.x, a4.y, a4.z, a4.w};
            const float b[4] = {b4.x, b4.y, b4.z, b4.w};
            #pragma unroll
            for (int i = 0; i < 4; ++i)
                #pragma unroll
                for (int j = 0; j < 4; ++j)
                    acc[i][j] = fmaf(a[i], b[j], acc[i][j]);
        }
        __syncthreads();
    }
    #pragma unroll
    for (int i = 0; i < 4; ++i){
        int m = m0 + ty * 4 + i;
        int o = o0 + tx * 4;
        if (o < O){
            float4 v;
            v.x = acc[i][0]; v.y = acc[i][1]; v.z = acc[i][2]; v.w = acc[i][3];
            if (bias){
                v.x += bias[o]; v.y += bias[o+1]; v.z += bias[o+2]; v.w += bias[o+3];
            }
            *(float4*)(&Y[(size_t)m * ldy + o]) = v;
        }
    }
}

// ---------------- bf16 MFMA GEMM: Y(M,O) = X(M,K)bf16 @ W(O,K)bf16^T (+bias) ----------------
// m97 structure: 128x128 tile, BK=64, 4 waves 2x2, global_load_lds w=16, XOR chunk-swizzle.
// STATSF: fuse masked per-channel sum/sumsq accumulation (over ok rows) into the epilogue.
// AFFA: fuse per-K-channel affine+lrelu (BN of the PREVIOUS layer) into A staging.
template<bool OBF16, bool STATSF, bool AFFA>
__global__ __launch_bounds__(256) void gemm_bf16_mfma(
        const unsigned short* __restrict__ Xg, const unsigned short* __restrict__ Wg,
        void* __restrict__ Yv, const float* __restrict__ bias,
        int K, int ldx, int ldy,
        const unsigned char* __restrict__ ok, float* __restrict__ statsL,
        const float* __restrict__ scA, const float* __restrict__ shA)
{
    __shared__ unsigned short As[128 * 64];
    __shared__ unsigned short Bs[128 * 64];
    const int t = threadIdx.x;
    const int lane = t & 63;
    const int w = t >> 6;
    const int wr = w >> 1, wc = w & 1;
    const int m0 = blockIdx.x * 128;
    const int o0 = blockIdx.y * 128;

    f32x4 acc[4][4] = {};

    for (int k0 = 0; k0 < K; k0 += 64){
        #pragma unroll
        for (int i = 0; i < 4; ++i){
            int e = i * 256 + t;                 // chunk id (16B each)
            int row = e >> 3;                    // 0..127
            int c = (e & 7) ^ (row & 7);         // pre-swizzled SOURCE chunk (m173 pattern)
            int kk = k0 + c * 8;
            if constexpr (AFFA){
                uint4 a = *(const uint4*)(Xg + (size_t)(m0 + row) * ldx + kk);
                float4 s0 = *(const float4*)&scA[kk], s1 = *(const float4*)&scA[kk + 4];
                float4 h0 = *(const float4*)&shA[kk], h1 = *(const float4*)&shA[kk + 4];
                const float sc[8] = {s0.x,s0.y,s0.z,s0.w, s1.x,s1.y,s1.z,s1.w};
                const float sh[8] = {h0.x,h0.y,h0.z,h0.w, h1.x,h1.y,h1.z,h1.w};
                unsigned int wds[4] = {a.x, a.y, a.z, a.w};
                unsigned int ov[4];
                #pragma unroll
                for (int q = 0; q < 4; ++q){
                    float f0 = bf2f((unsigned short)(wds[q] & 0xffffu)) * sc[2*q]   + sh[2*q];
                    float f1 = bf2f((unsigned short)(wds[q] >> 16))     * sc[2*q+1] + sh[2*q+1];
                    f0 = (f0 > 0.f) ? f0 : 0.2f * f0;
                    f1 = (f1 > 0.f) ? f1 : 0.2f * f1;
                    ov[q] = packbf(f0, f1);
                }
                uint4 o4 = {ov[0], ov[1], ov[2], ov[3]};
                *(uint4*)&As[(size_t)e * 8] = o4;   // same linear LDS dest as gl16
            } else {
                gl16(Xg + (size_t)(m0 + row) * ldx + kk, &As[(size_t)e * 8]);
            }
            gl16(Wg + (size_t)(o0 + row) * K + kk, &Bs[(size_t)e * 8]);
        }
        __syncthreads();
        const int kq = lane >> 4;                // 0..3
        #pragma unroll
        for (int ks = 0; ks < 2; ++ks){
            bf16x8 a[4], b[4];
            #pragma unroll
            for (int mi = 0; mi < 4; ++mi){
                int r = wr * 64 + mi * 16 + (lane & 15);
                int ch = (ks * 4 + kq) ^ (r & 7);
                a[mi] = *(const bf16x8*)&As[r * 64 + ch * 8];
            }
            #pragma unroll
            for (int ni = 0; ni < 4; ++ni){
                int r = wc * 64 + ni * 16 + (lane & 15);
                int ch = (ks * 4 + kq) ^ (r & 7);
                b[ni] = *(const bf16x8*)&Bs[r * 64 + ch * 8];
            }
            #pragma unroll
            for (int mi = 0; mi < 4; ++mi)
                #pragma unroll
                for (int ni = 0; ni < 4; ++ni)
                    acc[mi][ni] = __builtin_amdgcn_mfma_f32_16x16x32_bf16(a[mi], b[ni], acc[mi][ni], 0, 0, 0);
        }
        __syncthreads();
    }

    // C/D layout (m89-verified): col = lane&15, row = (lane>>4)*4 + reg
    float s1l[4] = {}, s2l[4] = {};
    float bi[4];
    #pragma unroll
    for (int ni = 0; ni < 4; ++ni)
        bi[ni] = bias ? bias[o0 + wc * 64 + ni * 16 + (lane & 15)] : 0.f;

    #pragma unroll
    for (int mi = 0; mi < 4; ++mi){
        const int mbase = m0 + wr * 64 + mi * 16 + (lane >> 4) * 4;
        uchar4 okv = {1,1,1,1};
        if constexpr (STATSF) okv = *(const uchar4*)(ok + mbase);
        const unsigned char okarr[4] = {okv.x, okv.y, okv.z, okv.w};
        #pragma unroll
        for (int j = 0; j < 4; ++j){
            const int m = mbase + j;
            #pragma unroll
            for (int ni = 0; ni < 4; ++ni){
                int o = o0 + wc * 64 + ni * 16 + (lane & 15);
                float v = acc[mi][ni][j] + bi[ni];
                if constexpr (STATSF){
                    if (okarr[j]){ s1l[ni] += v; s2l[ni] += v * v; }
                }
                if constexpr (OBF16)
                    ((unsigned short*)Yv)[(size_t)m * ldy + o] = f2bf(v);
                else
                    ((float*)Yv)[(size_t)m * ldy + o] = v;
            }
        }
    }

    if constexpr (STATSF){
        #pragma unroll
        for (int ni = 0; ni < 4; ++ni){
            s1l[ni] += __shfl_xor(s1l[ni], 16); s1l[ni] += __shfl_xor(s1l[ni], 32);
            s2l[ni] += __shfl_xor(s2l[ni], 16); s2l[ni] += __shfl_xor(s2l[ni], 32);
        }
        if ((lane >> 4) == 0){
            float* S = statsL + (size_t)((blockIdx.x + blockIdx.y) & 3) * 2048;
            #pragma unroll
            for (int ni = 0; ni < 4; ++ni){
                int o = o0 + wc * 64 + ni * 16 + lane;
                unsafeAtomicAdd(&S[o],        s1l[ni]);
                unsafeAtomicAdd(&S[1024 + o], s2l[ni]);
            }
        }
    }
}

// ---------------- edge gather: round-11 shape + compacted list + LDS-staged stats ----------------
// lane=channel, 2 pts/wave, XCD-pinned batches, NT stores. Per-wave stats go to LDS slots
// (no atomics), block-reduced across the 4 waves, then ONE global atomic per (channel,moment)
// per block into 8 replicas: 4x fewer atomic ops, 8x less per-address contention.
template<int T>  // T = O/64
__global__ __launch_bounds__(256) void edge_gather_kernel(
        const float* __restrict__ HHp, const int* __restrict__ ci,
        const unsigned char* __restrict__ okc, const float* __restrict__ g,
        float* __restrict__ hmaxo, float* __restrict__ hmino,
        float* __restrict__ statsL)
{
    constexpr int O = 64 * T, TWO2 = 2 * O;
    __shared__ float ls[4][2][64 * T];
    const int bid  = blockIdx.x;                 // MN/8 blocks
    const int wv   = threadIdx.x >> 6;
    const int lane = threadIdx.x & 63;
    const int bat  = bid & 7;                    // batch == XCD (round-robin dispatch)
    const int chunk = bid >> 3;
    const int base = bat << 11;
    const int p0   = base + chunk * 8 + wv * 2;

    bool ln = false;
    #pragma unroll
    for (int t = 0; t < T; ++t) if (g[lane + 64 * t] < 0.f) ln = true;
    const bool needmin = (__ballot(ln) != 0ull);

    float s1[T] = {}, s2[T] = {};
    #pragma unroll
    for (int pi = 0; pi < 2; ++pi){
        const int p = p0 + pi;
        const int cnt = okc[p];
        int jj[KNB];
        const int4* ip4 = (const int4*)(ci + (size_t)p * KNB);
        #pragma unroll
        for (int q = 0; q < 5; ++q){
            int4 iv = ip4[q];
            jj[q*4+0] = iv.x; jj[q*4+1] = iv.y; jj[q*4+2] = iv.z; jj[q*4+3] = iv.w;
        }
        float hc[T], hmax[T], hmin[T];
        #pragma unroll
        for (int t = 0; t < T; ++t){
            hc[t] = HHp[(size_t)p * TWO2 + O + lane + 64 * t];
            hmax[t] = -INFINITY; hmin[t] = INFINITY;
        }
        if (needmin){
            int k = 0;
            for (; k + 4 <= cnt; k += 4){
                #pragma unroll
                for (int u = 0; u < 4; ++u){
                    const float* row = HHp + (size_t)(base + jj[k + u]) * TWO2 + lane;
                    #pragma unroll
                    for (int t = 0; t < T; ++t){
                        float h = row[64 * t] + hc[t];
                        s1[t] += h; s2[t] += h * h;
                        hmax[t] = fmaxf(hmax[t], h);
                        hmin[t] = fminf(hmin[t], h);
                    }
                }
            }
            for (; k < cnt; ++k){
                const float* row = HHp + (size_t)(base + jj[k]) * TWO2 + lane;
                #pragma unroll
                for (int t = 0; t < T; ++t){
                    float h = row[64 * t] + hc[t];
                    s1[t] += h; s2[t] += h * h;
                    hmax[t] = fmaxf(hmax[t], h);
                    hmin[t] = fminf(hmin[t], h);
                }
            }
        } else {
            int k = 0;
            for (; k + 4 <= cnt; k += 4){
                #pragma unroll
                for (int u = 0; u < 4; ++u){
                    const float* row = HHp + (size_t)(base + jj[k + u]) * TWO2 + lane;
                    #pragma unroll
                    for (int t = 0; t < T; ++t){
                        float h = row[64 * t] + hc[t];
                        s1[t] += h; s2[t] += h * h;
                        hmax[t] = fmaxf(hmax[t], h);
                    }
                }
            }
            for (; k < cnt; ++k){
                const float* row = HHp + (size_t)(base + jj[k]) * TWO2 + lane;
                #pragma unroll
                for (int t = 0; t < T; ++t){
                    float h = row[64 * t] + hc[t];
                    s1[t] += h; s2[t] += h * h;
                    hmax[t] = fmaxf(hmax[t], h);
                }
            }
        }
        #pragma unroll
        for (int t = 0; t < T; ++t)
            __builtin_nontemporal_store(hmax[t], &hmaxo[(size_t)p * O + lane + 64 * t]);
        if (needmin){
            #pragma unroll
            for (int t = 0; t < T; ++t)
                __builtin_nontemporal_store(hmin[t], &hmino[(size_t)p * O + lane + 64 * t]);
        }
    }
    // stats: LDS slots (unique per wave/lane), block reduce, 1 atomic per value per block
    #pragma unroll
    for (int t = 0; t < T; ++t){
        ls[wv][0][64 * t + lane] = s1[t];
        ls[wv][1][64 * t + lane] = s2[t];
    }
    __syncthreads();
    float* S = statsL + (size_t)(bid & 7) * 2048;
    for (int v = threadIdx.x; v < 128 * T; v += 256){
        const int half = v / (64 * T);
        const int ch   = v - half * 64 * T;
        float s = ls[0][half][ch] + ls[1][half][ch] + ls[2][half][ch] + ls[3][half][ch];
        unsafeAtomicAdd(&S[half * 1024 + ch], s);
    }
}

// ---------------- BN parameter computation (8 replicas) ----------------
__global__ void bn_params_kernel(const float* __restrict__ statsL, const float* __restrict__ cnt,
        const float* __restrict__ g, const float* __restrict__ bta,
        float* __restrict__ scale, float* __restrict__ shift, int O)
{
    int o = blockIdx.x * 256 + threadIdx.x;
    if (o >= O) return;
    float s1 = 0.f, s2 = 0.f;
    #pragma unroll
    for (int r = 0; r < 8; ++r){
        s1 += statsL[(size_t)r * 2048 + o];
        s2 += statsL[(size_t)r * 2048 + 1024 + o];
    }
    float n   = fmaxf(*cnt, 1.0f);
    float mu  = s1 / n;
    float var = fmaxf(s2 / n - mu * mu, 0.f);
    float sc  = g[o] * rsqrtf(var + EPS);
    scale[o] = sc;
    shift[o] = bta[o] - mu * sc;
}

// ---------------- edge finalize: affine+lrelu on masked max -> bf16 concat buffer ----------------
__global__ __launch_bounds__(256) void edge_finalize_kernel(
        const float* __restrict__ hmaxo, const float* __restrict__ hmino,
        const unsigned char* __restrict__ ok,
        const float* __restrict__ scale, const float* __restrict__ shift,
        unsigned short* __restrict__ xcat, int O, int chanoff)
{
    size_t i = (size_t)blockIdx.x * 256 + threadIdx.x;
    size_t p = i / (size_t)O;
    int o = (int)(i - p * (size_t)O);
    float v = 0.f;
    if (ok[p]){
        float sc = scale[o];
        float h;
        if (sc >= 0.f) h = hmaxo[i]; else h = hmino[i];
        v = h * sc + shift[o];
        v = (v > 0.f) ? v : 0.2f * v;
    }
    xcat[p * CAT_C + chanoff + o] = f2bf(v);
}

// ---------------- final transpose (B,N,32) -> (B,32,N) ----------------
__global__ __launch_bounds__(256) void transpose_out_kernel(const float* __restrict__ Y, float* __restrict__ out){
    int i = blockIdx.x * 256 + threadIdx.x;
    int n = i & (N_ - 1);
    int rest = i >> 11;
    int o = rest & 31;
    int b = rest >> 5;
    out[i] = Y[((((size_t)b * N_) + n) << 5) + o];
}

// ---------------- host side ----------------
extern "C" void kernel_launch(void* const* d_in, const int* in_sizes, int n_in,
                              void* d_out, int out_size, void* d_ws, size_t ws_size,
                              hipStream_t stream)
{
    const float* x        = (const float*)d_in[0];
    const int*   idx      = (const int*)  d_in[1];
    const void*  valid_rw = d_in[2];
    const float* enc_w[4] = {(const float*)d_in[3], (const float*)d_in[6], (const float*)d_in[9],  (const float*)d_in[12]};
    const float* enc_g[4] = {(const float*)d_in[4], (const float*)d_in[7], (const float*)d_in[10], (const float*)d_in[13]};
    const float* enc_b[4] = {(const float*)d_in[5], (const float*)d_in[8], (const float*)d_in[11], (const float*)d_in[14]};
    const float* last_w   = (const float*)d_in[15];
    const float* last_g   = (const float*)d_in[16];
    const float* last_b   = (const float*)d_in[17];
    const float* emb_w1   = (const float*)d_in[18];
    const float* emb_bi1  = (const float*)d_in[19];
    const float* emb_g1   = (const float*)d_in[20];
    const float* emb_b1   = (const float*)d_in[21];
    const float* emb_w2   = (const float*)d_in[22];
    const float* emb_bi2  = (const float*)d_in[23];
    const float* emb_g2   = (const float*)d_in[24];
    const float* emb_b2   = (const float*)d_in[25];
    const float* out_w    = (const float*)d_in[26];
    const float* out_bias = (const float*)d_in[27];

    float* ws = (float*)d_ws;
    int*   ci   = (int*)(ws + CIDX);
    unsigned char* ok8  = (unsigned char*)(ws + OK8);
    unsigned short* xcatb = (unsigned short*)(ws + XCATB);
    unsigned short* ylb   = (unsigned short*)(ws + YLB);
    unsigned short* wlastb = (unsigned short*)(ws + WLAST);
    unsigned short* wemb1b = (unsigned short*)(ws + WEMB1);
    unsigned short* wemb2b = (unsigned short*)(ws + WEMB2);
    float* nvalid = ws + MISC + 0;
    float* n_ok   = ws + MISC + 1;
    int*   flag   = (int*)(ws + MISC + 2);

    hipMemsetAsync(d_ws, 0, (MISC + 16) * sizeof(float), stream);

    detect_valid_kernel<<<1, 256, 0, stream>>>((const unsigned char*)valid_rw, flag);
    expand_ok_kernel<<<MN / 256, 256, 0, stream>>>(valid_rw, idx, ci, ok8, nvalid, n_ok, flag);
    transpose_x_kernel<<<MN / 256, 256, 0, stream>>>(x, ws + XT);
    convert3_bf16_kernel<<<(278528 + 255) / 256, 256, 0, stream>>>(last_w, emb_w1, emb_w2, wlastb, wemb1b, wemb2b);

    const int Cs[4]     = {3, 64, 64, 128};
    const int Os[4]     = {64, 64, 128, 256};
    const int inoff[4]  = {0, 0, 64, 128};
    const int outoff[4] = {0, 64, 128, 256};

    for (int L = 0; L < 4; ++L){
        const int C = Cs[L], O = Os[L], TWO2 = 2 * O;
        if (L == 0){
            build_wcomb_f32_kernel<<<(2*O*C + 255)/256, 256, 0, stream>>>(enc_w[L], ws + WENC, O, C);
            dim3 gg(MN / 64, TWO2 / 64);
            gemm_f32<<<gg, 256, 0, stream>>>(ws + XT, ws + WENC, ws + HHOFF, nullptr, MN, C, TWO2, 4, TWO2, nullptr, nullptr);
        } else {
            build_wcomb_bf16_kernel<<<(2*O*C + 255)/256, 256, 0, stream>>>(enc_w[L], (unsigned short*)(ws + WENC), O, C);
            dim3 gg(MN / 128, TWO2 / 128);
            gemm_bf16_mfma<false, false, false><<<gg, 256, 0, stream>>>(xcatb + inoff[L], (unsigned short*)(ws + WENC),
                    ws + HHOFF, nullptr, C, CAT_C, TWO2, nullptr, nullptr, nullptr, nullptr);
        }
        float* statsL = ws + STATS + (size_t)L * 8 * 2048;
        const int gather_blocks = MN / 8;   // 8 points/block, batch pinned to XCD
        switch (O / 64){
            case 1: edge_gather_kernel<1><<<gather_blocks, 256, 0, stream>>>(ws + HHOFF, ci, ok8, enc_g[L], ws + HMAXO, ws + HMINO, statsL); break;
            case 2: edge_gather_kernel<2><<<gather_blocks, 256, 0, stream>>>(ws + HHOFF, ci, ok8, enc_g[L], ws + HMAXO, ws + HMINO, statsL); break;
            case 4: edge_gather_kernel<4><<<gather_blocks, 256, 0, stream>>>(ws + HHOFF, ci, ok8, enc_g[L], ws + HMAXO, ws + HMINO, statsL); break;
        }
        float* scl = ws + SCALEO + (size_t)L * 1024;
        float* shf = ws + SHIFTO + (size_t)L * 1024;
        bn_params_kernel<<<(O + 255)/256, 256, 0, stream>>>(statsL, nvalid, enc_g[L], enc_b[L], scl, shf, O);
        edge_finalize_kernel<<<(int)(((size_t)MN * O) / 256), 256, 0, stream>>>(
            ws + HMAXO, ws + HMINO, ok8, scl, shf, xcatb, O, outoff[L]);
    }

    // dense bf16 layers: GEMM writes RAW output + fused masked stats; BN+lrelu of that
    // output is fused into the NEXT GEMM's A staging (scale/shift ready after bn_params).
    unsigned short* yemb1b = (unsigned short*)(ws + HMAXO);
    float* yemb2 = ws + HMINO;
    float* yout  = ws + HHOFF;

    float* scl4 = ws + SCALEO + 4 * 1024, *shf4 = ws + SHIFTO + 4 * 1024;
    float* scl5 = ws + SCALEO + 5 * 1024, *shf5 = ws + SHIFTO + 5 * 1024;
    float* scl6 = ws + SCALEO + 6 * 1024, *shf6 = ws + SHIFTO + 6 * 1024;

    // last: raw output ylb + stats
    {
        float* statsL = ws + STATS + (size_t)4 * 8 * 2048;
        dim3 gg(MN / 128, 1024 / 128);
        gemm_bf16_mfma<true, true, false><<<gg, 256, 0, stream>>>(xcatb, wlastb, ylb, nullptr, 512, CAT_C, 1024,
                ok8, statsL, nullptr, nullptr);
        bn_params_kernel<<<4, 256, 0, stream>>>(statsL, n_ok, last_g, last_b, scl4, shf4, 1024);
    }
    // emb1: A = bn_lrelu(ylb) fused via AFFA; raw output yemb1b + stats
    {
        float* statsL = ws + STATS + (size_t)5 * 8 * 2048;
        dim3 gg(MN / 128, 512 / 128);
        gemm_bf16_mfma<true, true, true><<<gg, 256, 0, stream>>>(ylb, wemb1b, yemb1b, emb_bi1, 1024, 1024, 512,
                ok8, statsL, scl4, shf4);
        bn_params_kernel<<<2, 256, 0, stream>>>(statsL, n_ok, emb_g1, emb_b1, scl5, shf5, 512);
    }
    // emb2: A = bn_lrelu(yemb1b) fused; raw f32 output yemb2 + stats
    {
        float* statsL = ws + STATS + (size_t)6 * 8 * 2048;
        dim3 gg(MN / 128, 128 / 128);
        gemm_bf16_mfma<false, true, true><<<gg, 256, 0, stream>>>(yemb1b, wemb2b, yemb2, emb_bi2, 512, 512, 128,
                ok8, statsL, scl5, shf5);
        bn_params_kernel<<<1, 256, 0, stream>>>(statsL, n_ok, emb_g2, emb_b2, scl6, shf6, 128);
    }
    // out layer (f32): X = bn_lrelu(yemb2) fused into staging; then transpose
    {
        dim3 gg(MN / 64, 1);
        gemm_f32<<<gg, 256, 0, stream>>>(yemb2, out_w, yout, out_bias, MN, 128, 32, 128, 32, scl6, shf6);
        transpose_out_kernel<<<(B_ * 32 * N_) / 256, 256, 0, stream>>>(yout, (float*)d_out);
    }
}

// Round 15
// 387.278 us; speedup vs baseline: 1.8119x; 1.0168x over previous
//
#include <hip/hip_runtime.h>
#include <hip/hip_bf16.h>
#include <cstdint>
#include <cstddef>

// ---------------- problem constants (fixed by setup_inputs) ----------------
constexpr int B_  = 8;
constexpr int N_  = 2048;
constexpr int KNB = 20;
constexpr int MN  = B_ * N_;        // 16384 points
constexpr int CAT_C = 512;          // concat channels 64+64+128+256
constexpr float EPS = 1e-5f;

typedef __attribute__((ext_vector_type(8))) short bf16x8;
typedef __attribute__((ext_vector_type(4))) float f32x4;

// ---------------- workspace layout (units: floats) ----------------
constexpr size_t alignup64(size_t x){ return (x + 63) & ~size_t(63); }
constexpr size_t STATS   = 0;                          // 7 layers * 8 replicas * 2048 (S1@+0, S2@+1024)
constexpr size_t NSTATS  = size_t(7) * 8 * 2048;       // 114688
constexpr size_t MISC    = STATS + NSTATS;             // [0]=nvalid [1]=n_ok [2]=flag
constexpr size_t SCALEO  = alignup64(MISC + 16);
constexpr size_t SHIFTO  = SCALEO + 7 * 1024;
constexpr size_t CIDX    = alignup64(SHIFTO + 7 * 1024);          // MN*KNB ints (compacted valid idx)
constexpr size_t OK8     = alignup64(CIDX + size_t(MN) * KNB);    // MN bytes (valid count per point)
constexpr size_t WENC    = alignup64(OK8 + (MN + 3) / 4);
constexpr size_t WLAST   = WENC  + 32768;    // 1024x512 bf16
constexpr size_t WEMB1   = WLAST + 262144;   // 512x1024 bf16
constexpr size_t WEMB2   = WEMB1 + 262144;   // 128x512 bf16
constexpr size_t XT      = WEMB2 + 32768;
constexpr size_t XCATB   = alignup64(XT + size_t(MN) * 4);   // bf16 MN x 512
constexpr size_t HHOFF   = XCATB + size_t(MN) * 256;         // f32 MN x 512
constexpr size_t HMAXO   = HHOFF + size_t(MN) * 512;         // f32 MN x 256
constexpr size_t HMINO   = HMAXO + size_t(MN) * 256;         // f32 MN x 256
constexpr size_t YLB     = HMINO + size_t(MN) * 256;         // bf16 MN x 1024 (raw, pre-BN)
// aliases after enc phase: yemb1_bf = HMAXO (bf16 MNx512, raw), yemb2_f32 = HMINO (f32 MNx128, raw),
//                          yout_f32 = HHOFF (f32 MNx32).  Total ~122 MB.

__device__ inline float bf2f(unsigned short u){
    unsigned int x = ((unsigned int)u) << 16;
    return __builtin_bit_cast(float, x);
}
__device__ inline unsigned short f2bf(float f){
    __hip_bfloat16 h = __float2bfloat16(f);
    return __builtin_bit_cast(unsigned short, h);
}
__device__ inline unsigned int packbf(float a, float b){
    return (unsigned int)f2bf(a) | ((unsigned int)f2bf(b) << 16);
}
__device__ inline float lrelu(float v){ return fmaxf(v, 0.2f * v); }  // exact: v>0->v, v<=0->0.2v
__device__ inline void gl16(const void* g, void* l){
    __builtin_amdgcn_global_load_lds(
        (const __attribute__((address_space(1))) void*)g,
        (__attribute__((address_space(3))) void*)l, 16, 0, 0);
}

// ---------------- small utility kernels ----------------

__global__ __launch_bounds__(256) void detect_valid_kernel(const unsigned char* __restrict__ v, int* __restrict__ flag){
    __shared__ int f;
    if (threadIdx.x == 0) f = 1;
    __syncthreads();
    int ok = 1;
    #pragma unroll
    for (int it = 0; it < 4; ++it){
        int g = threadIdx.x + it * 256;
        unsigned char b0 = v[4*g], b1 = v[4*g+1], b2 = v[4*g+2], b3 = v[4*g+3];
        if ((b1 | b2 | b3) != 0 || b0 > 1) ok = 0;
    }
    if (!ok) atomicAnd(&f, 0);
    __syncthreads();
    if (threadIdx.x == 0) *flag = f;
}

// Fused: decode valid, STABLE-compact the valid neighbor indices into ci, write cnt -> ok,
// accumulate nvalid & n_ok.
__global__ __launch_bounds__(256) void expand_ok_kernel(const void* __restrict__ vin,
        const int* __restrict__ idx, int* __restrict__ ci, unsigned char* __restrict__ ok,
        float* __restrict__ nvalid, float* __restrict__ n_ok, const int* __restrict__ flag){
    const int p = blockIdx.x * 256 + threadIdx.x;   // MN exact multiple of 256
    int jj[KNB];
    const int4* ip4 = (const int4*)(idx + (size_t)p * KNB);
    #pragma unroll
    for (int q = 0; q < 5; ++q){
        int4 iv = ip4[q];
        jj[q*4+0] = iv.x; jj[q*4+1] = iv.y; jj[q*4+2] = iv.z; jj[q*4+3] = iv.w;
    }
    bool val[KNB];
    if (*flag){
        const int* vi = ((const int*)vin) + (size_t)p * KNB;
        #pragma unroll
        for (int k = 0; k < KNB; ++k) val[k] = vi[k] != 0;
    } else {
        const unsigned char* vb = ((const unsigned char*)vin) + (size_t)p * KNB;
        #pragma unroll
        for (int k = 0; k < KNB; ++k) val[k] = vb[k] != 0;
    }
    int cnt = 0;
    int* dst = ci + (size_t)p * KNB;
    #pragma unroll
    for (int k = 0; k < KNB; ++k){
        if (val[k]) dst[cnt++] = jj[k];
    }
    ok[p] = (unsigned char)cnt;
    float fc = (float)cnt;
    #pragma unroll
    for (int o = 32; o > 0; o >>= 1) fc += __shfl_down(fc, o);
    unsigned long long m = __ballot(cnt != 0);
    if ((threadIdx.x & 63) == 0){
        if (fc > 0.f) unsafeAtomicAdd(nvalid, fc);
        if (m)        unsafeAtomicAdd(n_ok, (float)__popcll(m));
    }
}

// x (B,3,N) -> xT (B*N, 4) row-major (pad 4th with 0)
__global__ __launch_bounds__(256) void transpose_x_kernel(const float* __restrict__ x, float* __restrict__ xt){
    int i = blockIdx.x * 256 + threadIdx.x;
    if (i >= MN) return;
    int b = i / N_, n = i % N_;
    float4 v;
    v.x = x[(size_t)(b*3 + 0) * N_ + n];
    v.y = x[(size_t)(b*3 + 1) * N_ + n];
    v.z = x[(size_t)(b*3 + 2) * N_ + n];
    v.w = 0.f;
    ((float4*)xt)[i] = v;
}

// W (O,2C) -> Wcomb (2O,C) f32
__global__ __launch_bounds__(256) void build_wcomb_f32_kernel(const float* __restrict__ W, float* __restrict__ wc,
        int O, int C){
    int i = blockIdx.x * 256 + threadIdx.x;
    if (i >= 2 * O * C) return;
    int r = i / C, c = i % C;
    float v;
    if (r < O) v = W[(size_t)r * (2*C) + c];
    else       v = W[(size_t)(r-O) * (2*C) + C + c] - W[(size_t)(r-O) * (2*C) + c];
    wc[i] = v;
}

// same but emits bf16
__global__ __launch_bounds__(256) void build_wcomb_bf16_kernel(const float* __restrict__ W, unsigned short* __restrict__ wc,
        int O, int C){
    int i = blockIdx.x * 256 + threadIdx.x;
    if (i >= 2 * O * C) return;
    int r = i / C, c = i % C;
    float v;
    if (r < O) v = W[(size_t)r * (2*C) + c];
    else       v = W[(size_t)(r-O) * (2*C) + C + c] - W[(size_t)(r-O) * (2*C) + c];
    wc[i] = f2bf(v);
}

// all three dense-weight conversions in one kernel (f32 -> bf16, float4 granules)
__global__ __launch_bounds__(256) void convert3_bf16_kernel(
        const float* __restrict__ a, const float* __restrict__ b, const float* __restrict__ c,
        unsigned short* __restrict__ wa, unsigned short* __restrict__ wb, unsigned short* __restrict__ wcc){
    int i = blockIdx.x * 256 + threadIdx.x;
    if (i >= 278528) return;
    const float* src; unsigned short* dst; int off;
    if (i < 131072)      { src = a; dst = wa;  off = i; }
    else if (i < 262144) { src = b; dst = wb;  off = i - 131072; }
    else                 { src = c; dst = wcc; off = i - 262144; }
    float4 v = ((const float4*)src)[off];
    ushort4 o;
    o.x = f2bf(v.x); o.y = f2bf(v.y); o.z = f2bf(v.z); o.w = f2bf(v.w);
    ((ushort4*)dst)[off] = o;
}

// ---------------- f32 tiled GEMM (enc1 K=3; out layer O=32 with optional fused BN+lrelu on X) ----------------
__global__ __launch_bounds__(256) void gemm_f32(
        const float* __restrict__ X, const float* __restrict__ W,
        float* __restrict__ Y, const float* __restrict__ bias,
        int M, int K, int O, int lda, int ldy,
        const float* __restrict__ scX, const float* __restrict__ shX)
{
    __shared__ float Xs[16][68];
    __shared__ float Ws[16][68];
    const int tid = threadIdx.x;
    const int tx = tid & 15, ty = tid >> 4;
    const int m0 = blockIdx.x * 64, o0 = blockIdx.y * 64;
    float acc[4][4] = {};
    for (int k0 = 0; k0 < K; k0 += 16){
        #pragma unroll
        for (int i = 0; i < 4; ++i){
            int e = tid + i * 256;
            int r = e >> 4, c = e & 15;
            float xv = 0.f, wv = 0.f;
            if (k0 + c < K){
                xv = X[(size_t)(m0 + r) * lda + k0 + c];
                if (scX){
                    xv = lrelu(xv * scX[k0 + c] + shX[k0 + c]);
                }
                if (o0 + r < O) wv = W[(size_t)(o0 + r) * K + k0 + c];
            }
            Xs[c][r] = xv;
            Ws[c][r] = wv;
        }
        __syncthreads();
        #pragma unroll
        for (int kk = 0; kk < 16; ++kk){
            const float4 a4 = *(const float4*)(&Xs[kk][ty * 4]);
            const float4 b4 = *(const float4*)(&Ws[kk][tx * 4]);
            const float a[4] = {a4.x, a4.y, a4.z, a4.w};
            const float b[4] = {b4.x, b4.y, b4.z, b4.w};
            #pragma unroll
            for (int i = 0; i < 4; ++i)
                #pragma unroll
                for (int j = 0; j < 4; ++j)
                    acc[i][j] = fmaf(a[i], b[j], acc[i][j]);
        }
        __syncthreads();
    }
    #pragma unroll
    for (int i = 0; i < 4; ++i){
        int m = m0 + ty * 4 + i;
        int o = o0 + tx * 4;
        if (o < O){
            float4 v;
            v.x = acc[i][0]; v.y = acc[i][1]; v.z = acc[i][2]; v.w = acc[i][3];
            if (bias){
                v.x += bias[o]; v.y += bias[o+1]; v.z += bias[o+2]; v.w += bias[o+3];
            }
            *(float4*)(&Y[(size_t)m * ldy + o]) = v;
        }
    }
}

// ---------------- bf16 MFMA GEMM: Y(M,O) = X(M,K)bf16 @ W(O,K)bf16^T (+bias) ----------------
// m97 structure: 128x128 tile, BK=64, 4 waves 2x2, global_load_lds w=16, XOR chunk-swizzle.
// STATSF: fuse masked per-channel sum/sumsq accumulation (over ok rows) into the epilogue.
// AFFA: fuse per-K-channel affine+lrelu (BN of the PREVIOUS layer) into A staging;
//       scale/shift preloaded into LDS once (K <= 1024).
template<bool OBF16, bool STATSF, bool AFFA>
__global__ __launch_bounds__(256) void gemm_bf16_mfma(
        const unsigned short* __restrict__ Xg, const unsigned short* __restrict__ Wg,
        void* __restrict__ Yv, const float* __restrict__ bias,
        int K, int ldx, int ldy,
        const unsigned char* __restrict__ ok, float* __restrict__ statsL,
        const float* __restrict__ scA, const float* __restrict__ shA)
{
    __shared__ unsigned short As[128 * 64];
    __shared__ unsigned short Bs[128 * 64];
    __shared__ float scsh[AFFA ? 2048 : 2];   // [0..K) = scale, [1024..1024+K) = shift
    const int t = threadIdx.x;
    const int lane = t & 63;
    const int w = t >> 6;
    const int wr = w >> 1, wc = w & 1;
    const int m0 = blockIdx.x * 128;
    const int o0 = blockIdx.y * 128;

    if constexpr (AFFA){
        for (int v = t; v < K; v += 256){
            scsh[v] = scA[v];
            scsh[1024 + v] = shA[v];
        }
        __syncthreads();
    }

    f32x4 acc[4][4] = {};

    for (int k0 = 0; k0 < K; k0 += 64){
        #pragma unroll
        for (int i = 0; i < 4; ++i){
            int e = i * 256 + t;                 // chunk id (16B each)
            int row = e >> 3;                    // 0..127
            int c = (e & 7) ^ (row & 7);         // pre-swizzled SOURCE chunk (m173 pattern)
            int kk = k0 + c * 8;
            if constexpr (AFFA){
                uint4 a = *(const uint4*)(Xg + (size_t)(m0 + row) * ldx + kk);
                float4 s0 = *(const float4*)&scsh[kk], s1 = *(const float4*)&scsh[kk + 4];
                float4 h0 = *(const float4*)&scsh[1024 + kk], h1 = *(const float4*)&scsh[1024 + kk + 4];
                const float sc[8] = {s0.x,s0.y,s0.z,s0.w, s1.x,s1.y,s1.z,s1.w};
                const float sh[8] = {h0.x,h0.y,h0.z,h0.w, h1.x,h1.y,h1.z,h1.w};
                unsigned int wds[4] = {a.x, a.y, a.z, a.w};
                unsigned int ov[4];
                #pragma unroll
                for (int q = 0; q < 4; ++q){
                    float f0 = lrelu(bf2f((unsigned short)(wds[q] & 0xffffu)) * sc[2*q]   + sh[2*q]);
                    float f1 = lrelu(bf2f((unsigned short)(wds[q] >> 16))     * sc[2*q+1] + sh[2*q+1]);
                    ov[q] = packbf(f0, f1);
                }
                uint4 o4 = {ov[0], ov[1], ov[2], ov[3]};
                *(uint4*)&As[(size_t)e * 8] = o4;   // same linear LDS dest as gl16
            } else {
                gl16(Xg + (size_t)(m0 + row) * ldx + kk, &As[(size_t)e * 8]);
            }
            gl16(Wg + (size_t)(o0 + row) * K + kk, &Bs[(size_t)e * 8]);
        }
        __syncthreads();
        const int kq = lane >> 4;                // 0..3
        #pragma unroll
        for (int ks = 0; ks < 2; ++ks){
            bf16x8 a[4], b[4];
            #pragma unroll
            for (int mi = 0; mi < 4; ++mi){
                int r = wr * 64 + mi * 16 + (lane & 15);
                int ch = (ks * 4 + kq) ^ (r & 7);
                a[mi] = *(const bf16x8*)&As[r * 64 + ch * 8];
            }
            #pragma unroll
            for (int ni = 0; ni < 4; ++ni){
                int r = wc * 64 + ni * 16 + (lane & 15);
                int ch = (ks * 4 + kq) ^ (r & 7);
                b[ni] = *(const bf16x8*)&Bs[r * 64 + ch * 8];
            }
            #pragma unroll
            for (int mi = 0; mi < 4; ++mi)
                #pragma unroll
                for (int ni = 0; ni < 4; ++ni)
                    acc[mi][ni] = __builtin_amdgcn_mfma_f32_16x16x32_bf16(a[mi], b[ni], acc[mi][ni], 0, 0, 0);
        }
        __syncthreads();
    }

    // C/D layout (m89-verified): col = lane&15, row = (lane>>4)*4 + reg
    float s1l[4] = {}, s2l[4] = {};
    float bi[4];
    #pragma unroll
    for (int ni = 0; ni < 4; ++ni)
        bi[ni] = bias ? bias[o0 + wc * 64 + ni * 16 + (lane & 15)] : 0.f;

    #pragma unroll
    for (int mi = 0; mi < 4; ++mi){
        const int mbase = m0 + wr * 64 + mi * 16 + (lane >> 4) * 4;
        uchar4 okv = {1,1,1,1};
        if constexpr (STATSF) okv = *(const uchar4*)(ok + mbase);
        const unsigned char okarr[4] = {okv.x, okv.y, okv.z, okv.w};
        #pragma unroll
        for (int j = 0; j < 4; ++j){
            const int m = mbase + j;
            #pragma unroll
            for (int ni = 0; ni < 4; ++ni){
                int o = o0 + wc * 64 + ni * 16 + (lane & 15);
                float v = acc[mi][ni][j] + bi[ni];
                if constexpr (STATSF){
                    if (okarr[j]){ s1l[ni] += v; s2l[ni] += v * v; }
                }
                if constexpr (OBF16)
                    ((unsigned short*)Yv)[(size_t)m * ldy + o] = f2bf(v);
                else
                    ((float*)Yv)[(size_t)m * ldy + o] = v;
            }
        }
    }

    if constexpr (STATSF){
        #pragma unroll
        for (int ni = 0; ni < 4; ++ni){
            s1l[ni] += __shfl_xor(s1l[ni], 16); s1l[ni] += __shfl_xor(s1l[ni], 32);
            s2l[ni] += __shfl_xor(s2l[ni], 16); s2l[ni] += __shfl_xor(s2l[ni], 32);
        }
        if ((lane >> 4) == 0){
            float* S = statsL + (size_t)((blockIdx.x + blockIdx.y) & 7) * 2048;
            #pragma unroll
            for (int ni = 0; ni < 4; ++ni){
                int o = o0 + wc * 64 + ni * 16 + lane;
                unsafeAtomicAdd(&S[o],        s1l[ni]);
                unsafeAtomicAdd(&S[1024 + o], s2l[ni]);
            }
        }
    }
}

// ---------------- edge gather: compacted list + LDS-staged stats ----------------
// lane=channel, 2 pts/wave, XCD-pinned batches, NT stores. Per-wave stats go to LDS slots
// (no atomics), block-reduced, then ONE global atomic per (channel,moment) per block into
// 8 replicas. hmin path only when some gamma<0.
template<int T>  // T = O/64
__global__ __launch_bounds__(256) void edge_gather_kernel(
        const float* __restrict__ HHp, const int* __restrict__ ci,
        const unsigned char* __restrict__ okc, const float* __restrict__ g,
        float* __restrict__ hmaxo, float* __restrict__ hmino,
        float* __restrict__ statsL)
{
    constexpr int O = 64 * T, TWO2 = 2 * O;
    __shared__ float ls[4][2][64 * T];
    const int bid  = blockIdx.x;                 // MN/8 blocks
    const int wv   = threadIdx.x >> 6;
    const int lane = threadIdx.x & 63;
    const int bat  = bid & 7;                    // batch == XCD (round-robin dispatch)
    const int chunk = bid >> 3;
    const int base = bat << 11;
    const int p0   = base + chunk * 8 + wv * 2;

    bool ln = false;
    #pragma unroll
    for (int t = 0; t < T; ++t) if (g[lane + 64 * t] < 0.f) ln = true;
    const bool needmin = (__ballot(ln) != 0ull);

    float s1[T] = {}, s2[T] = {};
    #pragma unroll
    for (int pi = 0; pi < 2; ++pi){
        const int p = p0 + pi;
        const int cnt = okc[p];
        int jj[KNB];
        const int4* ip4 = (const int4*)(ci + (size_t)p * KNB);
        #pragma unroll
        for (int q = 0; q < 5; ++q){
            int4 iv = ip4[q];
            jj[q*4+0] = iv.x; jj[q*4+1] = iv.y; jj[q*4+2] = iv.z; jj[q*4+3] = iv.w;
        }
        float hc[T], hmax[T], hmin[T];
        #pragma unroll
        for (int t = 0; t < T; ++t){
            hc[t] = HHp[(size_t)p * TWO2 + O + lane + 64 * t];
            hmax[t] = -INFINITY; hmin[t] = INFINITY;
        }
        if (needmin){
            int k = 0;
            for (; k + 4 <= cnt; k += 4){
                #pragma unroll
                for (int u = 0; u < 4; ++u){
                    const float* row = HHp + (size_t)(base + jj[k + u]) * TWO2 + lane;
                    #pragma unroll
                    for (int t = 0; t < T; ++t){
                        float h = row[64 * t] + hc[t];
                        s1[t] += h; s2[t] += h * h;
                        hmax[t] = fmaxf(hmax[t], h);
                        hmin[t] = fminf(hmin[t], h);
                    }
                }
            }
            for (; k < cnt; ++k){
                const float* row = HHp + (size_t)(base + jj[k]) * TWO2 + lane;
                #pragma unroll
                for (int t = 0; t < T; ++t){
                    float h = row[64 * t] + hc[t];
                    s1[t] += h; s2[t] += h * h;
                    hmax[t] = fmaxf(hmax[t], h);
                    hmin[t] = fminf(hmin[t], h);
                }
            }
        } else {
            int k = 0;
            for (; k + 4 <= cnt; k += 4){
                #pragma unroll
                for (int u = 0; u < 4; ++u){
                    const float* row = HHp + (size_t)(base + jj[k + u]) * TWO2 + lane;
                    #pragma unroll
                    for (int t = 0; t < T; ++t){
                        float h = row[64 * t] + hc[t];
                        s1[t] += h; s2[t] += h * h;
                        hmax[t] = fmaxf(hmax[t], h);
                    }
                }
            }
            for (; k < cnt; ++k){
                const float* row = HHp + (size_t)(base + jj[k]) * TWO2 + lane;
                #pragma unroll
                for (int t = 0; t < T; ++t){
                    float h = row[64 * t] + hc[t];
                    s1[t] += h; s2[t] += h * h;
                    hmax[t] = fmaxf(hmax[t], h);
                }
            }
        }
        #pragma unroll
        for (int t = 0; t < T; ++t)
            __builtin_nontemporal_store(hmax[t], &hmaxo[(size_t)p * O + lane + 64 * t]);
        if (needmin){
            #pragma unroll
            for (int t = 0; t < T; ++t)
                __builtin_nontemporal_store(hmin[t], &hmino[(size_t)p * O + lane + 64 * t]);
        }
    }
    // stats: LDS slots (unique per wave/lane), block reduce, 1 atomic per value per block
    #pragma unroll
    for (int t = 0; t < T; ++t){
        ls[wv][0][64 * t + lane] = s1[t];
        ls[wv][1][64 * t + lane] = s2[t];
    }
    __syncthreads();
    float* S = statsL + (size_t)(bid & 7) * 2048;
    for (int v = threadIdx.x; v < 128 * T; v += 256){
        const int half = v / (64 * T);
        const int ch   = v - half * 64 * T;
        float s = ls[0][half][ch] + ls[1][half][ch] + ls[2][half][ch] + ls[3][half][ch];
        unsafeAtomicAdd(&S[half * 1024 + ch], s);
    }
}

// ---------------- BN parameter computation (8 replicas) ----------------
__global__ void bn_params_kernel(const float* __restrict__ statsL, const float* __restrict__ cnt,
        const float* __restrict__ g, const float* __restrict__ bta,
        float* __restrict__ scale, float* __restrict__ shift, int O)
{
    int o = blockIdx.x * 256 + threadIdx.x;
    if (o >= O) return;
    float s1 = 0.f, s2 = 0.f;
    #pragma unroll
    for (int r = 0; r < 8; ++r){
        s1 += statsL[(size_t)r * 2048 + o];
        s2 += statsL[(size_t)r * 2048 + 1024 + o];
    }
    float n   = fmaxf(*cnt, 1.0f);
    float mu  = s1 / n;
    float var = fmaxf(s2 / n - mu * mu, 0.f);
    float sc  = g[o] * rsqrtf(var + EPS);
    scale[o] = sc;
    shift[o] = bta[o] - mu * sc;
}

// ---------------- edge finalize: affine+lrelu on masked max -> bf16 concat buffer ----------------
__global__ __launch_bounds__(256) void edge_finalize_kernel(
        const float* __restrict__ hmaxo, const float* __restrict__ hmino,
        const unsigned char* __restrict__ ok,
        const float* __restrict__ scale, const float* __restrict__ shift,
        unsigned short* __restrict__ xcat, int O, int chanoff)
{
    size_t i = (size_t)blockIdx.x * 256 + threadIdx.x;
    size_t p = i / (size_t)O;
    int o = (int)(i - p * (size_t)O);
    float v = 0.f;
    if (ok[p]){
        float sc = scale[o];
        float h;
        if (sc >= 0.f) h = hmaxo[i]; else h = hmino[i];
        v = lrelu(h * sc + shift[o]);
    }
    xcat[p * CAT_C + chanoff + o] = f2bf(v);
}

// ---------------- final transpose (B,N,32) -> (B,32,N) ----------------
__global__ __launch_bounds__(256) void transpose_out_kernel(const float* __restrict__ Y, float* __restrict__ out){
    int i = blockIdx.x * 256 + threadIdx.x;
    int n = i & (N_ - 1);
    int rest = i >> 11;
    int o = rest & 31;
    int b = rest >> 5;
    out[i] = Y[((((size_t)b * N_) + n) << 5) + o];
}

// ---------------- host side ----------------
extern "C" void kernel_launch(void* const* d_in, const int* in_sizes, int n_in,
                              void* d_out, int out_size, void* d_ws, size_t ws_size,
                              hipStream_t stream)
{
    const float* x        = (const float*)d_in[0];
    const int*   idx      = (const int*)  d_in[1];
    const void*  valid_rw = d_in[2];
    const float* enc_w[4] = {(const float*)d_in[3], (const float*)d_in[6], (const float*)d_in[9],  (const float*)d_in[12]};
    const float* enc_g[4] = {(const float*)d_in[4], (const float*)d_in[7], (const float*)d_in[10], (const float*)d_in[13]};
    const float* enc_b[4] = {(const float*)d_in[5], (const float*)d_in[8], (const float*)d_in[11], (const float*)d_in[14]};
    const float* last_w   = (const float*)d_in[15];
    const float* last_g   = (const float*)d_in[16];
    const float* last_b   = (const float*)d_in[17];
    const float* emb_w1   = (const float*)d_in[18];
    const float* emb_bi1  = (const float*)d_in[19];
    const float* emb_g1   = (const float*)d_in[20];
    const float* emb_b1   = (const float*)d_in[21];
    const float* emb_w2   = (const float*)d_in[22];
    const float* emb_bi2  = (const float*)d_in[23];
    const float* emb_g2   = (const float*)d_in[24];
    const float* emb_b2   = (const float*)d_in[25];
    const float* out_w    = (const float*)d_in[26];
    const float* out_bias = (const float*)d_in[27];

    float* ws = (float*)d_ws;
    int*   ci   = (int*)(ws + CIDX);
    unsigned char* ok8  = (unsigned char*)(ws + OK8);
    unsigned short* xcatb = (unsigned short*)(ws + XCATB);
    unsigned short* ylb   = (unsigned short*)(ws + YLB);
    unsigned short* wlastb = (unsigned short*)(ws + WLAST);
    unsigned short* wemb1b = (unsigned short*)(ws + WEMB1);
    unsigned short* wemb2b = (unsigned short*)(ws + WEMB2);
    float* nvalid = ws + MISC + 0;
    float* n_ok   = ws + MISC + 1;
    int*   flag   = (int*)(ws + MISC + 2);

    hipMemsetAsync(d_ws, 0, (MISC + 16) * sizeof(float), stream);

    detect_valid_kernel<<<1, 256, 0, stream>>>((const unsigned char*)valid_rw, flag);
    expand_ok_kernel<<<MN / 256, 256, 0, stream>>>(valid_rw, idx, ci, ok8, nvalid, n_ok, flag);
    transpose_x_kernel<<<MN / 256, 256, 0, stream>>>(x, ws + XT);
    convert3_bf16_kernel<<<(278528 + 255) / 256, 256, 0, stream>>>(last_w, emb_w1, emb_w2, wlastb, wemb1b, wemb2b);

    const int Cs[4]     = {3, 64, 64, 128};
    const int Os[4]     = {64, 64, 128, 256};
    const int inoff[4]  = {0, 0, 64, 128};
    const int outoff[4] = {0, 64, 128, 256};

    for (int L = 0; L < 4; ++L){
        const int C = Cs[L], O = Os[L], TWO2 = 2 * O;
        if (L == 0){
            build_wcomb_f32_kernel<<<(2*O*C + 255)/256, 256, 0, stream>>>(enc_w[L], ws + WENC, O, C);
            dim3 gg(MN / 64, TWO2 / 64);
            gemm_f32<<<gg, 256, 0, stream>>>(ws + XT, ws + WENC, ws + HHOFF, nullptr, MN, C, TWO2, 4, TWO2, nullptr, nullptr);
        } else {
            build_wcomb_bf16_kernel<<<(2*O*C + 255)/256, 256, 0, stream>>>(enc_w[L], (unsigned short*)(ws + WENC), O, C);
            dim3 gg(MN / 128, TWO2 / 128);
            gemm_bf16_mfma<false, false, false><<<gg, 256, 0, stream>>>(xcatb + inoff[L], (unsigned short*)(ws + WENC),
                    ws + HHOFF, nullptr, C, CAT_C, TWO2, nullptr, nullptr, nullptr, nullptr);
        }
        float* statsL = ws + STATS + (size_t)L * 8 * 2048;
        const int gather_blocks = MN / 8;   // 8 points/block, batch pinned to XCD
        switch (O / 64){
            case 1: edge_gather_kernel<1><<<gather_blocks, 256, 0, stream>>>(ws + HHOFF, ci, ok8, enc_g[L], ws + HMAXO, ws + HMINO, statsL); break;
            case 2: edge_gather_kernel<2><<<gather_blocks, 256, 0, stream>>>(ws + HHOFF, ci, ok8, enc_g[L], ws + HMAXO, ws + HMINO, statsL); break;
            case 4: edge_gather_kernel<4><<<gather_blocks, 256, 0, stream>>>(ws + HHOFF, ci, ok8, enc_g[L], ws + HMAXO, ws + HMINO, statsL); break;
        }
        float* scl = ws + SCALEO + (size_t)L * 1024;
        float* shf = ws + SHIFTO + (size_t)L * 1024;
        bn_params_kernel<<<(O + 255)/256, 256, 0, stream>>>(statsL, nvalid, enc_g[L], enc_b[L], scl, shf, O);
        edge_finalize_kernel<<<(int)(((size_t)MN * O) / 256), 256, 0, stream>>>(
            ws + HMAXO, ws + HMINO, ok8, scl, shf, xcatb, O, outoff[L]);
    }

    // dense bf16 layers: GEMM writes RAW output + fused masked stats; BN+lrelu of that
    // output is fused into the NEXT GEMM's A staging (scale/shift ready after bn_params).
    unsigned short* yemb1b = (unsigned short*)(ws + HMAXO);
    float* yemb2 = ws + HMINO;
    float* yout  = ws + HHOFF;

    float* scl4 = ws + SCALEO + 4 * 1024, *shf4 = ws + SHIFTO + 4 * 1024;
    float* scl5 = ws + SCALEO + 5 * 1024, *shf5 = ws + SHIFTO + 5 * 1024;
    float* scl6 = ws + SCALEO + 6 * 1024, *shf6 = ws + SHIFTO + 6 * 1024;

    // last: raw output ylb + stats
    {
        float* statsL = ws + STATS + (size_t)4 * 8 * 2048;
        dim3 gg(MN / 128, 1024 / 128);
        gemm_bf16_mfma<true, true, false><<<gg, 256, 0, stream>>>(xcatb, wlastb, ylb, nullptr, 512, CAT_C, 1024,
                ok8, statsL, nullptr, nullptr);
        bn_params_kernel<<<4, 256, 0, stream>>>(statsL, n_ok, last_g, last_b, scl4, shf4, 1024);
    }
    // emb1: A = bn_lrelu(ylb) fused via AFFA; raw output yemb1b + stats
    {
        float* statsL = ws + STATS + (size_t)5 * 8 * 2048;
        dim3 gg(MN / 128, 512 / 128);
        gemm_bf16_mfma<true, true, true><<<gg, 256, 0, stream>>>(ylb, wemb1b, yemb1b, emb_bi1, 1024, 1024, 512,
                ok8, statsL, scl4, shf4);
        bn_params_kernel<<<2, 256, 0, stream>>>(statsL, n_ok, emb_g1, emb_b1, scl5, shf5, 512);
    }
    // emb2: A = bn_lrelu(yemb1b) fused; raw f32 output yemb2 + stats
    {
        float* statsL = ws + STATS + (size_t)6 * 8 * 2048;
        dim3 gg(MN / 128, 128 / 128);
        gemm_bf16_mfma<false, true, true><<<gg, 256, 0, stream>>>(yemb1b, wemb2b, yemb2, emb_bi2, 512, 512, 128,
                ok8, statsL, scl5, shf5);
        bn_params_kernel<<<1, 256, 0, stream>>>(statsL, n_ok, emb_g2, emb_b2, scl6, shf6, 128);
    }
    // out layer (f32): X = bn_lrelu(yemb2) fused into staging; then transpose
    {
        dim3 gg(MN / 64, 1);
        gemm_f32<<<gg, 256, 0, stream>>>(yemb2, out_w, yout, out_bias, MN, 128, 32, 128, 32, scl6, shf6);
        transpose_out_kernel<<<(B_ * 32 * N_) / 256, 256, 0, stream>>>(yout, (float*)d_out);
    }
}